// Round 14
// baseline (179.041 us; speedup 1.0000x reference)
//
#include <hip/hip_runtime.h>
#include <stdint.h>

#define NHEAD  16
#define SEQ    2048
#define DMODEL 1024
#define BATCH  4

typedef __attribute__((ext_vector_type(4))) float f32x4;
typedef __attribute__((ext_vector_type(8))) __bf16 bf16x8;
typedef __attribute__((ext_vector_type(8))) unsigned short u16x8;

__device__ __forceinline__ unsigned short f2bf(float f) {
    unsigned int u = __builtin_bit_cast(unsigned int, f);
    u += 0x7FFFu + ((u >> 16) & 1u);   // RNE
    return (unsigned short)(u >> 16);
}

__device__ __forceinline__ unsigned int cvt_pk_bf16(float lo, float hi) {
    unsigned int r;
    asm("v_cvt_pk_bf16_f32 %0, %1, %2" : "=v"(r) : "v"(lo), "v"(hi));
    return r;
}

__device__ __forceinline__ float max3f(float a, float b, float c) {
    float d;
    asm("v_max3_f32 %0, %1, %2, %3" : "=v"(d) : "v"(a), "v"(b), "v"(c));
    return d;
}

// async global->LDS, 16B per lane. LDS dest must be wave-uniform base + lane*16.
__device__ __forceinline__ void gload_lds16(const void* g, void* l) {
    __builtin_amdgcn_global_load_lds(
        (const __attribute__((address_space(1))) unsigned int*)(uintptr_t)g,
        (__attribute__((address_space(3))) unsigned int*)(uintptr_t)l,
        16, 0, 0);
}

__device__ __forceinline__ bf16x8 lds_frag(const unsigned short* p) {
    return __builtin_bit_cast(bf16x8, *(const u16x8*)p);
}

__device__ __forceinline__ bf16x8 gfrag(const unsigned short* p) {
    return __builtin_bit_cast(bf16x8, *(const u16x8*)p);
}

// ---------------- fused fp32 -> bf16 conversion (x + 4 weights, one launch) ----------------
__global__ __launch_bounds__(256) void cvt_all(const float* __restrict__ x,
                                               const float* __restrict__ w0,
                                               const float* __restrict__ w1,
                                               const float* __restrict__ w2,
                                               const float* __restrict__ w3,
                                               unsigned short* __restrict__ xb,
                                               unsigned short* __restrict__ wdst) {
    int b = blockIdx.x;
    const float* src;
    unsigned short* dst;
    int i;
    if (b < 8192) {
        src = x; dst = xb;
        i = b * 256 + threadIdx.x;
    } else {
        int wb = b - 8192;
        int which = wb >> 10;
        src = which == 0 ? w0 : which == 1 ? w1 : which == 2 ? w2 : w3;
        dst = wdst + (size_t)which * 1024 * 1024;
        i = (wb & 1023) * 256 + threadIdx.x;
    }
    float4 v = ((const float4*)src)[i];
    ushort4 o;
    o.x = f2bf(v.x); o.y = f2bf(v.y); o.z = f2bf(v.z); o.w = f2bf(v.w);
    ((ushort4*)dst)[i] = o;
}

// ---------------- 8-phase 256x256 QKV GEMM: [Q|K|V] = X(8192x1024) * Wcat(3072x1024)^T --------
// BM=BN=256, BK=64, 512 thr = 8 waves (2M x 4N). Wave frag i: row (i>>2)*128 + wm*64 + (i&3)*16
// (M interleaved across staging halves); frag j: col (j>>1)*128 + wn*32 + (j&1)*16.
// LDS 128KB: A[2dbuf][2half][128x64] + B same, chunk-XOR swizzled (chunk c of row r -> c^(r&7),
// pre-swizzled global source). Each phase: {ds_read one A-half or B-half, stage 1 half-tile,
// raw s_barrier, lgkmcnt(0)+sched_barrier, setprio(1) 16 MFMA setprio(0), s_barrier}.
// vmcnt(6) only at phases 4 and 8 (3 half-tiles in flight); never 0 except final iteration.
// Ledger: stage->slot: ph1:A[1][1]<-T1.A1  ph2:A[0][0]<-(T0+2).A0  ph3:B[0][0]<-(T0+2).B0
//   ph4:B[0][1]<-(T0+2).B1  ph5:A[0][1]<-(T0+2).A1  ph6:A[1][0]<-(T1+2).A0
//   ph7:B[1][0]<-(T1+2).B0  ph8:B[1][1]<-(T1+2).B1.  All slot reuses barrier-separated; all
//   stage->first-read deadlines covered by the vmcnt(6) points (checked exhaustively).
__global__ __launch_bounds__(512, 1) void gemm8_qkv(const unsigned short* __restrict__ A,
                                                    const unsigned short* __restrict__ Wc,
                                                    unsigned short* __restrict__ qw,
                                                    unsigned short* __restrict__ kw,
                                                    unsigned short* __restrict__ vw) {
    extern __shared__ __align__(16) unsigned short lds[];   // 65536 shorts = 128KB

    const int tid  = threadIdx.x;
    const int lane = tid & 63;
    const int wid  = tid >> 6;
    const int wm = wid >> 2, wn = wid & 3;
    const int l15 = lane & 15, lg = lane >> 4, l7 = l15 & 7;

    const int bx = blockIdx.x;              // 0..11 (0-3 Q, 4-7 K, 8-11 V)
    const int m0 = blockIdx.y * 256;
    const int n0 = bx * 256;

    auto STAGE_A = [&](int t, int h) {
        unsigned short* dst = lds + ((t & 1) * 2 + h) * 8192;
#pragma unroll
        for (int pass = 0; pass < 2; ++pass) {
            int ci = pass * 512 + tid;
            int row = ci >> 3, c = ci & 7;
            gload_lds16(A + (size_t)(m0 + h * 128 + row) * 1024 + t * 64 + ((c ^ (row & 7)) << 3),
                        dst + ci * 8);
        }
    };
    auto STAGE_B = [&](int t, int h) {
        unsigned short* dst = lds + 32768 + ((t & 1) * 2 + h) * 8192;
#pragma unroll
        for (int pass = 0; pass < 2; ++pass) {
            int ci = pass * 512 + tid;
            int row = ci >> 3, c = ci & 7;
            gload_lds16(Wc + (size_t)(n0 + h * 128 + row) * 1024 + t * 64 + ((c ^ (row & 7)) << 3),
                        dst + ci * 8);
        }
    };

    f32x4 acc[8][4];
#pragma unroll
    for (int i = 0; i < 8; i++)
#pragma unroll
        for (int j = 0; j < 4; j++) acc[i][j] = f32x4{0.f, 0.f, 0.f, 0.f};

    const int aoff = (wm * 64 + l15) * 64;   // + q*1024
    const int boff = (wn * 32 + l15) * 64;   // + s*1024
    const int cs0 = (lg ^ l7) << 3;
    const int cs1 = ((4 + lg) ^ l7) << 3;

    bf16x8 a8[8], b0[4], b1[4];

    // prologue: K0 all 4 half-tiles, then K1.A0, K1.B0, K1.B1 (K1.A1 staged at ph1)
    STAGE_A(0, 0); STAGE_B(0, 0); STAGE_B(0, 1); STAGE_A(0, 1);
    STAGE_A(1, 0); STAGE_B(1, 0); STAGE_B(1, 1);
    asm volatile("s_waitcnt vmcnt(6)" ::: "memory");   // K0's 4 landed; K1's 3 in flight
    __builtin_amdgcn_sched_barrier(0);
    __builtin_amdgcn_s_barrier();

    for (int it = 0; it < 8; ++it) {
        const int T0 = 2 * it, T1 = 2 * it + 1;
        const bool notlast = (it != 7);

        // ---- ph1 (T0, mh0, nh0): read A[0][0]->a8, B[0][0]->b0; stage A[1][1]<-T1.A1 ----
        {
            const unsigned short* As_ = lds;
            const unsigned short* Bs_ = lds + 32768;
#pragma unroll
            for (int q = 0; q < 4; q++) {
                a8[q * 2 + 0] = lds_frag(As_ + aoff + q * 1024 + cs0);
                a8[q * 2 + 1] = lds_frag(As_ + aoff + q * 1024 + cs1);
            }
#pragma unroll
            for (int s = 0; s < 2; s++) {
                b0[s * 2 + 0] = lds_frag(Bs_ + boff + s * 1024 + cs0);
                b0[s * 2 + 1] = lds_frag(Bs_ + boff + s * 1024 + cs1);
            }
            STAGE_A(T1, 1);
            __builtin_amdgcn_s_barrier();
            asm volatile("s_waitcnt lgkmcnt(0)" ::: "memory");
            __builtin_amdgcn_sched_barrier(0);
            __builtin_amdgcn_s_setprio(1);
#pragma unroll
            for (int q = 0; q < 4; q++)
#pragma unroll
                for (int s = 0; s < 2; s++) {
                    acc[q][s] = __builtin_amdgcn_mfma_f32_16x16x32_bf16(a8[q*2+0], b0[s*2+0], acc[q][s], 0, 0, 0);
                    acc[q][s] = __builtin_amdgcn_mfma_f32_16x16x32_bf16(a8[q*2+1], b0[s*2+1], acc[q][s], 0, 0, 0);
                }
            __builtin_amdgcn_s_setprio(0);
            __builtin_amdgcn_s_barrier();
        }
        // ---- ph2 (T0, mh0, nh1): read B[0][1]->b1; stage A[0][0]<-(T0+2).A0 ----
        {
            const unsigned short* Bs_ = lds + 32768 + 8192;
#pragma unroll
            for (int s = 0; s < 2; s++) {
                b1[s * 2 + 0] = lds_frag(Bs_ + boff + s * 1024 + cs0);
                b1[s * 2 + 1] = lds_frag(Bs_ + boff + s * 1024 + cs1);
            }
            if (notlast) STAGE_A(T0 + 2, 0);
            __builtin_amdgcn_s_barrier();
            asm volatile("s_waitcnt lgkmcnt(0)" ::: "memory");
            __builtin_amdgcn_sched_barrier(0);
            __builtin_amdgcn_s_setprio(1);
#pragma unroll
            for (int q = 0; q < 4; q++)
#pragma unroll
                for (int s = 0; s < 2; s++) {
                    acc[q][2+s] = __builtin_amdgcn_mfma_f32_16x16x32_bf16(a8[q*2+0], b1[s*2+0], acc[q][2+s], 0, 0, 0);
                    acc[q][2+s] = __builtin_amdgcn_mfma_f32_16x16x32_bf16(a8[q*2+1], b1[s*2+1], acc[q][2+s], 0, 0, 0);
                }
            __builtin_amdgcn_s_setprio(0);
            __builtin_amdgcn_s_barrier();
        }
        // ---- ph3 (T0, mh1, nh1): read A[0][1]->a8; stage B[0][0]<-(T0+2).B0 ----
        {
            const unsigned short* As_ = lds + 8192;
#pragma unroll
            for (int q = 0; q < 4; q++) {
                a8[q * 2 + 0] = lds_frag(As_ + aoff + q * 1024 + cs0);
                a8[q * 2 + 1] = lds_frag(As_ + aoff + q * 1024 + cs1);
            }
            if (notlast) STAGE_B(T0 + 2, 0);
            __builtin_amdgcn_s_barrier();
            asm volatile("s_waitcnt lgkmcnt(0)" ::: "memory");
            __builtin_amdgcn_sched_barrier(0);
            __builtin_amdgcn_s_setprio(1);
#pragma unroll
            for (int q = 0; q < 4; q++)
#pragma unroll
                for (int s = 0; s < 2; s++) {
                    acc[4+q][2+s] = __builtin_amdgcn_mfma_f32_16x16x32_bf16(a8[q*2+0], b1[s*2+0], acc[4+q][2+s], 0, 0, 0);
                    acc[4+q][2+s] = __builtin_amdgcn_mfma_f32_16x16x32_bf16(a8[q*2+1], b1[s*2+1], acc[4+q][2+s], 0, 0, 0);
                }
            __builtin_amdgcn_s_setprio(0);
            __builtin_amdgcn_s_barrier();
        }
        // ---- ph4 (T0, mh1, nh0): no reads (b0 live); stage B[0][1]<-(T0+2).B1; vmcnt ----
        {
            if (notlast) STAGE_B(T0 + 2, 1);
            __builtin_amdgcn_s_barrier();
            __builtin_amdgcn_s_setprio(1);
#pragma unroll
            for (int q = 0; q < 4; q++)
#pragma unroll
                for (int s = 0; s < 2; s++) {
                    acc[4+q][s] = __builtin_amdgcn_mfma_f32_16x16x32_bf16(a8[q*2+0], b0[s*2+0], acc[4+q][s], 0, 0, 0);
                    acc[4+q][s] = __builtin_amdgcn_mfma_f32_16x16x32_bf16(a8[q*2+1], b0[s*2+1], acc[4+q][s], 0, 0, 0);
                }
            __builtin_amdgcn_s_setprio(0);
            if (notlast) { asm volatile("s_waitcnt vmcnt(6)" ::: "memory"); }
            else         { asm volatile("s_waitcnt vmcnt(0)" ::: "memory"); }
            __builtin_amdgcn_sched_barrier(0);
            __builtin_amdgcn_s_barrier();
        }
        // ---- ph5 (T1, mh0, nh0): read A[1][0]->a8, B[1][0]->b0; stage A[0][1]<-(T0+2).A1 ----
        {
            const unsigned short* As_ = lds + 2 * 8192;
            const unsigned short* Bs_ = lds + 32768 + 2 * 8192;
#pragma unroll
            for (int q = 0; q < 4; q++) {
                a8[q * 2 + 0] = lds_frag(As_ + aoff + q * 1024 + cs0);
                a8[q * 2 + 1] = lds_frag(As_ + aoff + q * 1024 + cs1);
            }
#pragma unroll
            for (int s = 0; s < 2; s++) {
                b0[s * 2 + 0] = lds_frag(Bs_ + boff + s * 1024 + cs0);
                b0[s * 2 + 1] = lds_frag(Bs_ + boff + s * 1024 + cs1);
            }
            if (notlast) STAGE_A(T0 + 2, 1);
            __builtin_amdgcn_s_barrier();
            asm volatile("s_waitcnt lgkmcnt(0)" ::: "memory");
            __builtin_amdgcn_sched_barrier(0);
            __builtin_amdgcn_s_setprio(1);
#pragma unroll
            for (int q = 0; q < 4; q++)
#pragma unroll
                for (int s = 0; s < 2; s++) {
                    acc[q][s] = __builtin_amdgcn_mfma_f32_16x16x32_bf16(a8[q*2+0], b0[s*2+0], acc[q][s], 0, 0, 0);
                    acc[q][s] = __builtin_amdgcn_mfma_f32_16x16x32_bf16(a8[q*2+1], b0[s*2+1], acc[q][s], 0, 0, 0);
                }
            __builtin_amdgcn_s_setprio(0);
            __builtin_amdgcn_s_barrier();
        }
        // ---- ph6 (T1, mh0, nh1): read B[1][1]->b1; stage A[1][0]<-(T1+2).A0 ----
        {
            const unsigned short* Bs_ = lds + 32768 + 3 * 8192;
#pragma unroll
            for (int s = 0; s < 2; s++) {
                b1[s * 2 + 0] = lds_frag(Bs_ + boff + s * 1024 + cs0);
                b1[s * 2 + 1] = lds_frag(Bs_ + boff + s * 1024 + cs1);
            }
            if (notlast) STAGE_A(T1 + 2, 0);
            __builtin_amdgcn_s_barrier();
            asm volatile("s_waitcnt lgkmcnt(0)" ::: "memory");
            __builtin_amdgcn_sched_barrier(0);
            __builtin_amdgcn_s_setprio(1);
#pragma unroll
            for (int q = 0; q < 4; q++)
#pragma unroll
                for (int s = 0; s < 2; s++) {
                    acc[q][2+s] = __builtin_amdgcn_mfma_f32_16x16x32_bf16(a8[q*2+0], b1[s*2+0], acc[q][2+s], 0, 0, 0);
                    acc[q][2+s] = __builtin_amdgcn_mfma_f32_16x16x32_bf16(a8[q*2+1], b1[s*2+1], acc[q][2+s], 0, 0, 0);
                }
            __builtin_amdgcn_s_setprio(0);
            __builtin_amdgcn_s_barrier();
        }
        // ---- ph7 (T1, mh1, nh1): read A[1][1]->a8; stage B[1][0]<-(T1+2).B0 ----
        {
            const unsigned short* As_ = lds + 3 * 8192;
#pragma unroll
            for (int q = 0; q < 4; q++) {
                a8[q * 2 + 0] = lds_frag(As_ + aoff + q * 1024 + cs0);
                a8[q * 2 + 1] = lds_frag(As_ + aoff + q * 1024 + cs1);
            }
            if (notlast) STAGE_B(T1 + 2, 0);
            __builtin_amdgcn_s_barrier();
            asm volatile("s_waitcnt lgkmcnt(0)" ::: "memory");
            __builtin_amdgcn_sched_barrier(0);
            __builtin_amdgcn_s_setprio(1);
#pragma unroll
            for (int q = 0; q < 4; q++)
#pragma unroll
                for (int s = 0; s < 2; s++) {
                    acc[4+q][2+s] = __builtin_amdgcn_mfma_f32_16x16x32_bf16(a8[q*2+0], b1[s*2+0], acc[4+q][2+s], 0, 0, 0);
                    acc[4+q][2+s] = __builtin_amdgcn_mfma_f32_16x16x32_bf16(a8[q*2+1], b1[s*2+1], acc[4+q][2+s], 0, 0, 0);
                }
            __builtin_amdgcn_s_setprio(0);
            __builtin_amdgcn_s_barrier();
        }
        // ---- ph8 (T1, mh1, nh0): no reads; stage B[1][1]<-(T1+2).B1; vmcnt ----
        {
            if (notlast) STAGE_B(T1 + 2, 1);
            __builtin_amdgcn_s_barrier();
            __builtin_amdgcn_s_setprio(1);
#pragma unroll
            for (int q = 0; q < 4; q++)
#pragma unroll
                for (int s = 0; s < 2; s++) {
                    acc[4+q][s] = __builtin_amdgcn_mfma_f32_16x16x32_bf16(a8[q*2+0], b0[s*2+0], acc[4+q][s], 0, 0, 0);
                    acc[4+q][s] = __builtin_amdgcn_mfma_f32_16x16x32_bf16(a8[q*2+1], b0[s*2+1], acc[4+q][s], 0, 0, 0);
                }
            __builtin_amdgcn_s_setprio(0);
            if (notlast) { asm volatile("s_waitcnt vmcnt(6)" ::: "memory"); }
            else         { asm volatile("s_waitcnt vmcnt(0)" ::: "memory"); }
            __builtin_amdgcn_sched_barrier(0);
            __builtin_amdgcn_s_barrier();
        }
    }

    // epilogue: m = m0 + (i>>2)*128 + wm*64 + (i&3)*16 + lg*4 + r
    //           n_op = (bx&3)*256 + (j>>1)*128 + wn*32 + (j&1)*16 + l15
    const int opnd = bx >> 2;   // 0 Q, 1 K, 2 V
    if (opnd == 2) {            // V -> (b,h,dk,s) transposed
#pragma unroll
        for (int i = 0; i < 8; i++)
#pragma unroll
            for (int r = 0; r < 4; r++) {
                int m = m0 + (i >> 2) * 128 + wm * 64 + (i & 3) * 16 + lg * 4 + r;
                int b = m >> 11, s = m & 2047;
#pragma unroll
                for (int j = 0; j < 4; j++) {
                    int n_op = (bx & 3) * 256 + (j >> 1) * 128 + wn * 32 + (j & 1) * 16 + l15;
                    int h = n_op >> 6, dk = n_op & 63;
                    vw[((size_t)(b * NHEAD + h) * 64 + dk) * SEQ + s] = f2bf(acc[i][j][r]);
                }
            }
    } else {                    // Q or K with RoPE -> (b,h,s,dk); Q pre-scaled by 1/8*log2e
        unsigned short* out = (opnd == 0) ? qw : kw;
        const float qscale = (opnd == 0) ? 0.18033688011112042f : 1.0f;
        const float L2T = 13.287712379549449f;   // log2(10000)
        float invf[4];
#pragma unroll
        for (int j = 0; j < 4; j++) {
            int idx = (wn & 1) * 32 + (j & 1) * 16 + l15;   // dk
            int t = idx >> 1;
            invf[j] = exp2f(-((float)(2 * t) * (1.0f / 64.0f)) * L2T);
        }
        const int par = l15 & 1;
#pragma unroll
        for (int i = 0; i < 8; i++)
#pragma unroll
            for (int r = 0; r < 4; r++) {
                int m = m0 + (i >> 2) * 128 + wm * 64 + (i & 3) * 16 + lg * 4 + r;
                int b = m >> 11, s = m & 2047;
                float fs = (float)s;
#pragma unroll
                for (int j = 0; j < 4; j++) {
                    float v = acc[i][j][r];
                    float other = __shfl_xor(v, 1);
                    float sn, cs;
                    __sincosf(fs * invf[j], &sn, &cs);
                    float y = par ? fmaf(v, cs, other * sn) : fmaf(v, cs, -other * sn);
                    y *= qscale;
                    int n_op = (bx & 3) * 256 + (j >> 1) * 128 + wn * 32 + (j & 1) * 16 + l15;
                    int h = n_op >> 6, dk = n_op & 63;
                    out[((size_t)(b * NHEAD + h) * SEQ + s) * 64 + dk] = f2bf(y);
                }
            }
    }
}

// ---------------- output GEMM: d_out = OW(8192x1024) * Wo(1024x1024)^T, fp32 out ----------------
__global__ __launch_bounds__(256) void gemm_out(const unsigned short* __restrict__ A,
                                                const unsigned short* __restrict__ W,
                                                float* __restrict__ out) {
    __shared__ __align__(16) unsigned short As[2][128 * 64];
    __shared__ __align__(16) unsigned short Bs[2][128 * 64];

    const int tid  = threadIdx.x;
    const int lane = tid & 63;
    const int wid  = tid >> 6;
    const int wm = wid >> 1, wn = wid & 1;
    const int l15 = lane & 15, lg = lane >> 4;

    const int tn = blockIdx.x & 7;
    const int tm = blockIdx.x >> 3;
    const int m0 = tm * 128, n0 = tn * 128;

    f32x4 acc[4][4];
#pragma unroll
    for (int i = 0; i < 4; i++)
#pragma unroll
        for (int j = 0; j < 4; j++) acc[i][j] = f32x4{0.f, 0.f, 0.f, 0.f};

    const int e0 = tid * 8;
    auto STAGE = [&](int kk, int bufi) {
#pragma unroll
        for (int is = 0; is < 4; ++is) {
            int e = is * 2048 + e0;
            int row = e >> 6, col = e & 63;
            gload_lds16(A + (size_t)(m0 + row) * 1024 + kk + col, &As[bufi][e]);
            gload_lds16(W + (size_t)(n0 + row) * 1024 + kk + col, &Bs[bufi][e]);
        }
    };

    STAGE(0, 0);
    __syncthreads();

    for (int kk = 0; kk < 1024; kk += 64) {
        const int cur = (kk >> 6) & 1;
        if (kk + 64 < 1024) STAGE(kk + 64, cur ^ 1);
#pragma unroll
        for (int ks = 0; ks < 2; ++ks) {
            bf16x8 a[4], b[4];
#pragma unroll
            for (int f = 0; f < 4; f++) {
                a[f] = lds_frag(&As[cur][(wm * 64 + f * 16 + l15) * 64 + ks * 32 + lg * 8]);
                b[f] = lds_frag(&Bs[cur][(wn * 64 + f * 16 + l15) * 64 + ks * 32 + lg * 8]);
            }
#pragma unroll
            for (int i = 0; i < 4; i++)
#pragma unroll
                for (int j = 0; j < 4; j++)
                    acc[i][j] = __builtin_amdgcn_mfma_f32_16x16x32_bf16(a[i], b[j], acc[i][j], 0, 0, 0);
        }
        __syncthreads();
    }

#pragma unroll
    for (int i = 0; i < 4; i++)
#pragma unroll
        for (int r = 0; r < 4; r++) {
            int m = m0 + wm * 64 + i * 16 + lg * 4 + r;
            float* orow = out + (size_t)m * 1024 + n0 + wn * 64 + l15;
#pragma unroll
            for (int j = 0; j < 4; j++) orow[j * 16] = acc[i][j][r];
        }
}

// ---------------- causal flash attention: concatenated balanced pairing ----------------
// (unchanged from round 13: C-init=-mrun softmax, ones-MFMA row-sum, defer-max, XOR swizzle)
__global__ __launch_bounds__(256, 4) void flash_attn(const unsigned short* __restrict__ Qw,
                                                     const unsigned short* __restrict__ Kw,
                                                     const unsigned short* __restrict__ Vw,
                                                     unsigned short* __restrict__ Ow) {
    __shared__ __align__(16) unsigned short Ks[2][64 * 64];
    __shared__ __align__(16) unsigned short Vs[2][64 * 64];   // [dk][kv]
    __shared__ __align__(16) unsigned short Ps[64 * 64];      // [q][kv], swizzled, reused A/B

    const int tid  = threadIdx.x;
    const int lane = tid & 63;
    const int w    = tid >> 6;
    const int l15 = lane & 15, lg = lane >> 4;
    const int l7 = l15 & 7;

    const int logical = (blockIdx.x & 7) * 128 + (blockIdx.x >> 3);
    const int bh = logical >> 4;
    const int p  = logical & 15;       // pair: q-tiles p and 31-p
    const int qbB = 31 - p;

    const unsigned short* Kbh = Kw + (size_t)bh * (SEQ * 64);
    const unsigned short* Vbh = Vw + (size_t)bh * (64 * SEQ);

    const int qrow0 = w * 16;
    const int prow  = qrow0 + l15;

    const unsigned short* QrowA = Qw + (size_t)bh * (SEQ * 64) + (size_t)(p * 64 + prow) * 64;
    const unsigned short* QrowB = Qw + (size_t)bh * (SEQ * 64) + (size_t)(qbB * 64 + prow) * 64;
    bf16x8 qA0 = gfrag(QrowA + lg * 8), qA1 = gfrag(QrowA + 32 + lg * 8);
    bf16x8 qB0 = gfrag(QrowB + lg * 8), qB1 = gfrag(QrowB + 32 + lg * 8);

    u16x8 onesu = {0x3F80, 0x3F80, 0x3F80, 0x3F80, 0x3F80, 0x3F80, 0x3F80, 0x3F80};
    const bf16x8 vones = __builtin_bit_cast(bf16x8, onesu);   // bf16 1.0 x8

    auto STAGE = [&](int kt2, int bufi) {
#pragma unroll
        for (int is = 0; is < 2; ++is) {
            int e = (is * 256 + tid) * 8;
            int row = e >> 6, c = (e >> 3) & 7;
            int sc = (c ^ (row & 7)) << 3;
            gload_lds16(Kbh + (size_t)kt2 * 4096 + row * 64 + sc, &Ks[bufi][e]);
            gload_lds16(Vbh + (size_t)row * SEQ + kt2 * 64 + sc, &Vs[bufi][e]);
        }
    };

    STAGE(0, 0);

    f32x4 oaccA[4], oaccB[4];
#pragma unroll
    for (int f = 0; f < 4; f++) { oaccA[f] = f32x4{0.f, 0.f, 0.f, 0.f}; oaccB[f] = f32x4{0.f, 0.f, 0.f, 0.f}; }
    f32x4 accA5 = f32x4{0.f, 0.f, 0.f, 0.f}, accB5 = f32x4{0.f, 0.f, 0.f, 0.f};   // row-sums l
    float mA = 0.f, mB = 0.f;   // running max (log2 domain), shift tracked via C-init

    unsigned short* pbase = &Ps[prow * 64];
    const unsigned short* prd = &Ps[prow * 64];

    int cur = 0;
    __syncthreads();

    auto PROC = [&](bf16x8 q0, bf16x8 q1, f32x4* oacc, f32x4& acc5, float& mrun, bool diag) {
        f32x4 st[4];
        const f32x4 cinit = {-mrun, -mrun, -mrun, -mrun};
        __builtin_amdgcn_s_setprio(1);
#pragma unroll
        for (int f = 0; f < 4; f++) {
            bf16x8 kfrag = lds_frag(&Ks[cur][(f * 16 + l15) * 64 + ((lg ^ l7) << 3)]);
            st[f] = __builtin_amdgcn_mfma_f32_16x16x32_bf16(kfrag, q0, cinit, 0, 0, 0);
        }
#pragma unroll
        for (int f = 0; f < 4; f++) {
            bf16x8 kfrag = lds_frag(&Ks[cur][(f * 16 + l15) * 64 + (((4 + lg) ^ l7) << 3)]);
            st[f] = __builtin_amdgcn_mfma_f32_16x16x32_bf16(kfrag, q1, st[f], 0, 0, 0);
        }
        __builtin_amdgcn_s_setprio(0);

        if (diag) {
#pragma unroll
            for (int f = 0; f < 4; f++)
#pragma unroll
                for (int r = 0; r < 4; r++) {
                    int kv = f * 16 + 4 * lg + r;
                    if (kv > prow) st[f][r] = -3.0e38f;
                }
        }

        float m1 = max3f(st[0][0], st[0][1], st[0][2]);
        float m2 = max3f(st[0][3], st[1][0], st[1][1]);
        float m3 = max3f(st[1][2], st[1][3], st[2][0]);
        float m4 = max3f(st[2][1], st[2][2], st[2][3]);
        float m5 = max3f(st[3][0], st[3][1], st[3][2]);
        float pm = fmaxf(max3f(m1, m2, m3), max3f(m4, m5, st[3][3]));
        pm = fmaxf(pm, __shfl_xor(pm, 16));
        pm = fmaxf(pm, __shfl_xor(pm, 32));

        if (!__all(pm <= 8.0f)) {
            float d = fmaxf(pm, 0.0f);
            float sc0 = exp2f(-d);
            mrun += d;
#pragma unroll
            for (int f = 0; f < 4; f++)
#pragma unroll
                for (int r = 0; r < 4; r++) st[f][r] -= d;
#pragma unroll
            for (int r = 0; r < 4; r++) {
                float so = __shfl(sc0, lg * 4 + r);
#pragma unroll
                for (int f = 0; f < 4; f++) oacc[f][r] *= so;
                acc5[r] *= so;
            }
        }

#pragma unroll
        for (int f = 0; f < 4; f++)
#pragma unroll
            for (int r = 0; r < 4; r++)
                st[f][r] = exp2f(st[f][r]);

        {
            const int halfoff = (lg & 1) << 2;
            const int cbase = lg >> 1;
#pragma unroll
            for (int f = 0; f < 4; f++) {
                uint2 pw;
                pw.x = cvt_pk_bf16(st[f][0], st[f][1]);
                pw.y = cvt_pk_bf16(st[f][2], st[f][3]);
                *(uint2*)(pbase + (((2 * f + cbase) ^ l7) << 3) + halfoff) = pw;
            }
        }

        __builtin_amdgcn_s_setprio(1);
#pragma unroll
        for (int ks = 0; ks < 2; ++ks) {
            bf16x8 pa = lds_frag(prd + (((ks * 4 + lg) ^ l7) << 3));
#pragma unroll
            for (int f = 0; f < 4; f++) {
                bf16x8 vb = lds_frag(&Vs[cur][(f * 16 + l15) * 64 + (((ks * 4 + lg) ^ l7) << 3)]);
                oacc[f] = __builtin_amdgcn_mfma_f32_16x16x32_bf16(pa, vb, oacc[f], 0, 0, 0);
            }
            acc5 = __builtin_amdgcn_mfma_f32_16x16x32_bf16(pa, vones, acc5, 0, 0, 0);
        }
        __builtin_amdgcn_s_setprio(0);
    };

    for (int kt = 0; kt <= p; ++kt) {
        if (kt < p) STAGE(kt + 1, cur ^ 1);
        else        STAGE(0, cur ^ 1);
        PROC(qA0, qA1, oaccA, accA5, mA, kt == p);
        __syncthreads();
        cur ^= 1;
    }
    for (int kt = 0; kt <= qbB; ++kt) {
        if (kt < qbB) STAGE(kt + 1, cur ^ 1);
        PROC(qB0, qB1, oaccB, accB5, mB, kt == qbB);
        __syncthreads();
        cur ^= 1;
    }

    const int b = bh >> 4, h = bh & 15;
#pragma unroll
    for (int r = 0; r < 4; r++) {
        float invA = 1.0f / accA5[r];
        int sgA = p * 64 + qrow0 + lg * 4 + r;
        unsigned short* orowA = Ow + ((size_t)(b * SEQ + sgA) * DMODEL) + h * 64 + l15;
#pragma unroll
        for (int f = 0; f < 4; f++) orowA[f * 16] = f2bf(oaccA[f][r] * invA);

        float invB = 1.0f / accB5[r];
        int sgB = qbB * 64 + qrow0 + lg * 4 + r;
        unsigned short* orowB = Ow + ((size_t)(b * SEQ + sgB) * DMODEL) + h * 64 + l15;
#pragma unroll
        for (int f = 0; f < 4; f++) orowB[f * 16] = f2bf(oaccB[f][r] * invB);
    }
}

extern "C" void kernel_launch(void* const* d_in, const int* in_sizes, int n_in,
                              void* d_out, int out_size, void* d_ws, size_t ws_size,
                              hipStream_t stream) {
    const float* x  = (const float*)d_in[0];
    const float* wq = (const float*)d_in[1];
    const float* wk = (const float*)d_in[2];
    const float* wv = (const float*)d_in[3];
    const float* wo = (const float*)d_in[4];

    unsigned short* ws = (unsigned short*)d_ws;
    const size_t MEL = (size_t)8192 * 1024;   // 8M elements
    const size_t WEL = (size_t)1024 * 1024;   // 1M elements
    unsigned short* xb  = ws;
    unsigned short* wqb = xb + MEL;           // 4 weights contiguous: wq|wk|wv|wo
    unsigned short* wob = wqb + 3 * WEL;
    unsigned short* qw  = wob + WEL;
    unsigned short* kw  = qw + MEL;
    unsigned short* vw  = kw + MEL;
    unsigned short* ow  = vw + MEL;

    const int QKV_LDS = 131072;   // 128 KB dynamic
    (void)hipFuncSetAttribute((const void*)gemm8_qkv,
                              hipFuncAttributeMaxDynamicSharedMemorySize, QKV_LDS);

    cvt_all<<<12288, 256, 0, stream>>>(x, wq, wk, wv, wo, xb, wqb);

    gemm8_qkv<<<dim3(12, 32), 512, QKV_LDS, stream>>>(xb, wqb, qw, kw, vw);

    flash_attn<<<1024, 256, 0, stream>>>(qw, kw, vw, ow);

    gemm_out<<<512, 256, 0, stream>>>(ow, wob, (float*)d_out);
}

// Round 15
// 176.938 us; speedup vs baseline: 1.0119x; 1.0119x over previous
//
#include <hip/hip_runtime.h>
#include <stdint.h>

#define NHEAD  16
#define SEQ    2048
#define DMODEL 1024
#define BATCH  4

typedef __attribute__((ext_vector_type(4))) float f32x4;
typedef __attribute__((ext_vector_type(8))) __bf16 bf16x8;
typedef __attribute__((ext_vector_type(8))) unsigned short u16x8;

__device__ __forceinline__ unsigned short f2bf(float f) {
    unsigned int u = __builtin_bit_cast(unsigned int, f);
    u += 0x7FFFu + ((u >> 16) & 1u);   // RNE
    return (unsigned short)(u >> 16);
}

__device__ __forceinline__ unsigned int cvt_pk_bf16(float lo, float hi) {
    unsigned int r;
    asm("v_cvt_pk_bf16_f32 %0, %1, %2" : "=v"(r) : "v"(lo), "v"(hi));
    return r;
}

__device__ __forceinline__ float max3f(float a, float b, float c) {
    float d;
    asm("v_max3_f32 %0, %1, %2, %3" : "=v"(d) : "v"(a), "v"(b), "v"(c));
    return d;
}

// async global->LDS, 16B per lane. LDS dest must be wave-uniform base + lane*16.
__device__ __forceinline__ void gload_lds16(const void* g, void* l) {
    __builtin_amdgcn_global_load_lds(
        (const __attribute__((address_space(1))) unsigned int*)(uintptr_t)g,
        (__attribute__((address_space(3))) unsigned int*)(uintptr_t)l,
        16, 0, 0);
}

__device__ __forceinline__ bf16x8 lds_frag(const unsigned short* p) {
    return __builtin_bit_cast(bf16x8, *(const u16x8*)p);
}

__device__ __forceinline__ bf16x8 gfrag(const unsigned short* p) {
    return __builtin_bit_cast(bf16x8, *(const u16x8*)p);
}

// ---------------- fused fp32 -> bf16 conversion (x + 4 weights, one launch) ----------------
__global__ __launch_bounds__(256) void cvt_all(const float* __restrict__ x,
                                               const float* __restrict__ w0,
                                               const float* __restrict__ w1,
                                               const float* __restrict__ w2,
                                               const float* __restrict__ w3,
                                               unsigned short* __restrict__ xb,
                                               unsigned short* __restrict__ wdst) {
    int b = blockIdx.x;
    const float* src;
    unsigned short* dst;
    int i;
    if (b < 8192) {
        src = x; dst = xb;
        i = b * 256 + threadIdx.x;
    } else {
        int wb = b - 8192;
        int which = wb >> 10;
        src = which == 0 ? w0 : which == 1 ? w1 : which == 2 ? w2 : w3;
        dst = wdst + (size_t)which * 1024 * 1024;
        i = (wb & 1023) * 256 + threadIdx.x;
    }
    float4 v = ((const float4*)src)[i];
    ushort4 o;
    o.x = f2bf(v.x); o.y = f2bf(v.y); o.z = f2bf(v.z); o.w = f2bf(v.w);
    ((ushort4*)dst)[i] = o;
}

// ---------------- fused QKV GEMM: [Q|K|V] = X(8192x1024) * Wcat(3072x1024)^T ----------------
// grid (24, 64): x = n-tile (0-7 Q, 8-15 K, 16-23 V), y = m-tile
// Q output is pre-scaled by 1/8*log2(e) so flash softmax works directly in log2 domain.
__global__ __launch_bounds__(256) void gemm_qkv(const unsigned short* __restrict__ A,
                                                const unsigned short* __restrict__ Wc,
                                                unsigned short* __restrict__ qw,
                                                unsigned short* __restrict__ kw,
                                                unsigned short* __restrict__ vw) {
    __shared__ __align__(16) unsigned short As[2][128 * 64];
    __shared__ __align__(16) unsigned short Bs[2][128 * 64];

    const int tid  = threadIdx.x;
    const int lane = tid & 63;
    const int wid  = tid >> 6;
    const int wm = wid >> 1, wn = wid & 1;
    const int l15 = lane & 15, lg = lane >> 4;

    const int tn = blockIdx.x;
    const int m0 = blockIdx.y * 128, n0 = tn * 128;

    f32x4 acc[4][4];
#pragma unroll
    for (int i = 0; i < 4; i++)
#pragma unroll
        for (int j = 0; j < 4; j++) acc[i][j] = f32x4{0.f, 0.f, 0.f, 0.f};

    const int e0 = tid * 8;
    auto STAGE = [&](int kk, int bufi) {
#pragma unroll
        for (int is = 0; is < 4; ++is) {
            int e = is * 2048 + e0;
            int row = e >> 6, col = e & 63;
            gload_lds16(A  + (size_t)(m0 + row) * 1024 + kk + col, &As[bufi][e]);
            gload_lds16(Wc + (size_t)(n0 + row) * 1024 + kk + col, &Bs[bufi][e]);
        }
    };

    STAGE(0, 0);
    __syncthreads();

    for (int kk = 0; kk < 1024; kk += 64) {
        const int cur = (kk >> 6) & 1;
        if (kk + 64 < 1024) STAGE(kk + 64, cur ^ 1);
#pragma unroll
        for (int ks = 0; ks < 2; ++ks) {
            bf16x8 a[4], b[4];
#pragma unroll
            for (int f = 0; f < 4; f++) {
                a[f] = lds_frag(&As[cur][(wm * 64 + f * 16 + l15) * 64 + ks * 32 + lg * 8]);
                b[f] = lds_frag(&Bs[cur][(wn * 64 + f * 16 + l15) * 64 + ks * 32 + lg * 8]);
            }
#pragma unroll
            for (int i = 0; i < 4; i++)
#pragma unroll
                for (int j = 0; j < 4; j++)
                    acc[i][j] = __builtin_amdgcn_mfma_f32_16x16x32_bf16(a[i], b[j], acc[i][j], 0, 0, 0);
        }
        __syncthreads();
    }

    if (tn >= 16) {   // V -> (b,h,dk,s) transposed
        unsigned short* out = vw;
#pragma unroll
        for (int i = 0; i < 4; i++)
#pragma unroll
            for (int r = 0; r < 4; r++) {
                int m = m0 + wm * 64 + i * 16 + lg * 4 + r;
                int b = m >> 11, s = m & 2047;
#pragma unroll
                for (int j = 0; j < 4; j++) {
                    int n = n0 + wn * 64 + j * 16 + l15;
                    int h = (n >> 6) & 15, dk = n & 63;
                    out[((size_t)(b * NHEAD + h) * 64 + dk) * SEQ + s] = f2bf(acc[i][j][r]);
                }
            }
    } else {          // Q or K with RoPE -> (b,h,s,dk)
        unsigned short* out = (tn < 8) ? qw : kw;
        const float qscale = (tn < 8) ? 0.18033688011112042f : 1.0f;   // 1/8*log2(e) for Q
        const float L2T = 13.287712379549449f;   // log2(10000)
        float invf[4];
#pragma unroll
        for (int j = 0; j < 4; j++) {
            int idx = j * 16 + l15;          // n % 64
            int t = idx >> 1;
            invf[j] = exp2f(-((float)(2 * t) * (1.0f / 64.0f)) * L2T);
        }
        const int par = l15 & 1;
#pragma unroll
        for (int i = 0; i < 4; i++)
#pragma unroll
            for (int r = 0; r < 4; r++) {
                int m = m0 + wm * 64 + i * 16 + lg * 4 + r;
                int b = m >> 11, s = m & 2047;
                float fs = (float)s;
#pragma unroll
                for (int j = 0; j < 4; j++) {
                    float v = acc[i][j][r];
                    float other = __shfl_xor(v, 1);
                    float sn, cs;
                    __sincosf(fs * invf[j], &sn, &cs);
                    float y = par ? fmaf(v, cs, other * sn) : fmaf(v, cs, -other * sn);
                    y *= qscale;
                    int n = n0 + wn * 64 + j * 16 + l15;
                    int h = (n >> 6) & 15, dk = n & 63;
                    out[((size_t)(b * NHEAD + h) * SEQ + s) * 64 + dk] = f2bf(y);
                }
            }
    }
}

// ---------------- output GEMM: d_out = OW(8192x1024) * Wo(1024x1024)^T, fp32 out ----------------
__global__ __launch_bounds__(256) void gemm_out(const unsigned short* __restrict__ A,
                                                const unsigned short* __restrict__ W,
                                                float* __restrict__ out) {
    __shared__ __align__(16) unsigned short As[2][128 * 64];
    __shared__ __align__(16) unsigned short Bs[2][128 * 64];

    const int tid  = threadIdx.x;
    const int lane = tid & 63;
    const int wid  = tid >> 6;
    const int wm = wid >> 1, wn = wid & 1;
    const int l15 = lane & 15, lg = lane >> 4;

    const int tn = blockIdx.x & 7;
    const int tm = blockIdx.x >> 3;
    const int m0 = tm * 128, n0 = tn * 128;

    f32x4 acc[4][4];
#pragma unroll
    for (int i = 0; i < 4; i++)
#pragma unroll
        for (int j = 0; j < 4; j++) acc[i][j] = f32x4{0.f, 0.f, 0.f, 0.f};

    const int e0 = tid * 8;
    auto STAGE = [&](int kk, int bufi) {
#pragma unroll
        for (int is = 0; is < 4; ++is) {
            int e = is * 2048 + e0;
            int row = e >> 6, col = e & 63;
            gload_lds16(A + (size_t)(m0 + row) * 1024 + kk + col, &As[bufi][e]);
            gload_lds16(W + (size_t)(n0 + row) * 1024 + kk + col, &Bs[bufi][e]);
        }
    };

    STAGE(0, 0);
    __syncthreads();

    for (int kk = 0; kk < 1024; kk += 64) {
        const int cur = (kk >> 6) & 1;
        if (kk + 64 < 1024) STAGE(kk + 64, cur ^ 1);
#pragma unroll
        for (int ks = 0; ks < 2; ++ks) {
            bf16x8 a[4], b[4];
#pragma unroll
            for (int f = 0; f < 4; f++) {
                a[f] = lds_frag(&As[cur][(wm * 64 + f * 16 + l15) * 64 + ks * 32 + lg * 8]);
                b[f] = lds_frag(&Bs[cur][(wn * 64 + f * 16 + l15) * 64 + ks * 32 + lg * 8]);
            }
#pragma unroll
            for (int i = 0; i < 4; i++)
#pragma unroll
                for (int j = 0; j < 4; j++)
                    acc[i][j] = __builtin_amdgcn_mfma_f32_16x16x32_bf16(a[i], b[j], acc[i][j], 0, 0, 0);
        }
        __syncthreads();
    }

#pragma unroll
    for (int i = 0; i < 4; i++)
#pragma unroll
        for (int r = 0; r < 4; r++) {
            int m = m0 + wm * 64 + i * 16 + lg * 4 + r;
            float* orow = out + (size_t)m * 1024 + n0 + wn * 64 + l15;
#pragma unroll
            for (int j = 0; j < 4; j++) orow[j * 16] = acc[i][j][r];
        }
}

// ---------------- causal flash attention: balanced pairing (tile p + tile 31-p) ----------------
// Q,K in (bh, s, dk) (Q pre-scaled by 1/8*log2e); V in (bh, dk, s). Out (b,s,dmodel) bf16.
// QK^T MFMA C-operand initialized to -mrun: scores come out of the MFMA already max-shifted,
// removing the 16 v_sub before exp2 on the deferred (common) path. mrun starts at 0.
// Row-sum l via ones-MFMA (acc5); alternating-perm p remap for iteration balance.
__global__ __launch_bounds__(256, 4) void flash_attn(const unsigned short* __restrict__ Qw,
                                                     const unsigned short* __restrict__ Kw,
                                                     const unsigned short* __restrict__ Vw,
                                                     unsigned short* __restrict__ Ow) {
    __shared__ __align__(16) unsigned short Ks[2][64 * 64];
    __shared__ __align__(16) unsigned short Vs[2][64 * 64];   // [dk][kv]
    __shared__ __align__(16) unsigned short Ps[64 * 64];      // [q][kv], swizzled, reused A/B

    const int tid  = threadIdx.x;
    const int lane = tid & 63;
    const int w    = tid >> 6;
    const int l15 = lane & 15, lg = lane >> 4;
    const int l7 = l15 & 7;

    const int logical = (blockIdx.x & 7) * 128 + (blockIdx.x >> 3);
    const int bh = logical >> 4;
    const int idx = logical & 15;
    const int g = (logical >> 5) & 15;
    const int j = (idx + g) & 15;
    const int p = (j & 1) ? (15 - (j >> 1)) : (j >> 1);   // pair: q-tiles p and 31-p
    const int qbB = 31 - p;
    const int ktmax = qbB;

    const unsigned short* Kbh = Kw + (size_t)bh * (SEQ * 64);
    const unsigned short* Vbh = Vw + (size_t)bh * (64 * SEQ);

    const int qrow0 = w * 16;
    const int prow  = qrow0 + l15;

    const unsigned short* QrowA = Qw + (size_t)bh * (SEQ * 64) + (size_t)(p * 64 + prow) * 64;
    const unsigned short* QrowB = Qw + (size_t)bh * (SEQ * 64) + (size_t)(qbB * 64 + prow) * 64;
    bf16x8 qA0 = gfrag(QrowA + lg * 8), qA1 = gfrag(QrowA + 32 + lg * 8);
    bf16x8 qB0 = gfrag(QrowB + lg * 8), qB1 = gfrag(QrowB + 32 + lg * 8);

    u16x8 onesu = {0x3F80, 0x3F80, 0x3F80, 0x3F80, 0x3F80, 0x3F80, 0x3F80, 0x3F80};
    const bf16x8 vones = __builtin_bit_cast(bf16x8, onesu);   // bf16 1.0 x8

    auto STAGE = [&](int kt2, int bufi) {
#pragma unroll
        for (int is = 0; is < 2; ++is) {
            int e = (is * 256 + tid) * 8;
            int row = e >> 6, c = (e >> 3) & 7;
            int sc = (c ^ (row & 7)) << 3;
            gload_lds16(Kbh + (size_t)kt2 * 4096 + row * 64 + sc, &Ks[bufi][e]);
            gload_lds16(Vbh + (size_t)row * SEQ + kt2 * 64 + sc, &Vs[bufi][e]);
        }
    };

    STAGE(0, 0);

    f32x4 oaccA[4], oaccB[4];
#pragma unroll
    for (int f = 0; f < 4; f++) { oaccA[f] = f32x4{0.f, 0.f, 0.f, 0.f}; oaccB[f] = f32x4{0.f, 0.f, 0.f, 0.f}; }
    f32x4 accA5 = f32x4{0.f, 0.f, 0.f, 0.f}, accB5 = f32x4{0.f, 0.f, 0.f, 0.f};   // row-sums l
    float mA = 0.f, mB = 0.f;   // running max (log2 domain), relative-shift tracked via C-init

    unsigned short* pbase = &Ps[prow * 64];
    const unsigned short* prd = &Ps[prow * 64];

    __syncthreads();

    for (int kt = 0; kt <= ktmax; ++kt) {
        const int cur = kt & 1;
        if (kt < ktmax) STAGE(kt + 1, cur ^ 1);

        auto PROC = [&](bf16x8 q0, bf16x8 q1, f32x4* oacc, f32x4& acc5, float& mrun, bool diag) {
            // S^T = K·Q with C init = -mrun: st = S - mrun directly out of the MFMA
            f32x4 st[4];
            const f32x4 cinit = {-mrun, -mrun, -mrun, -mrun};
            __builtin_amdgcn_s_setprio(1);
#pragma unroll
            for (int f = 0; f < 4; f++) {
                bf16x8 kfrag = lds_frag(&Ks[cur][(f * 16 + l15) * 64 + ((lg ^ l7) << 3)]);
                st[f] = __builtin_amdgcn_mfma_f32_16x16x32_bf16(kfrag, q0, cinit, 0, 0, 0);
            }
#pragma unroll
            for (int f = 0; f < 4; f++) {
                bf16x8 kfrag = lds_frag(&Ks[cur][(f * 16 + l15) * 64 + (((4 + lg) ^ l7) << 3)]);
                st[f] = __builtin_amdgcn_mfma_f32_16x16x32_bf16(kfrag, q1, st[f], 0, 0, 0);
            }
            __builtin_amdgcn_s_setprio(0);

            if (diag) {
#pragma unroll
                for (int f = 0; f < 4; f++)
#pragma unroll
                    for (int r = 0; r < 4; r++) {
                        int kv = f * 16 + 4 * lg + r;
                        if (kv > prow) st[f][r] = -3.0e38f;
                    }
            }

            // per-q max of (S - mrun): 7 max3 + 1 fmax in-lane, then 2 shuffles
            float m1 = max3f(st[0][0], st[0][1], st[0][2]);
            float m2 = max3f(st[0][3], st[1][0], st[1][1]);
            float m3 = max3f(st[1][2], st[1][3], st[2][0]);
            float m4 = max3f(st[2][1], st[2][2], st[2][3]);
            float m5 = max3f(st[3][0], st[3][1], st[3][2]);
            float pm = fmaxf(max3f(m1, m2, m3), max3f(m4, m5, st[3][3]));
            pm = fmaxf(pm, __shfl_xor(pm, 16));
            pm = fmaxf(pm, __shfl_xor(pm, 32));

            // defer-max (T13): rescale only when some row grew by > 8 over mrun
            if (!__all(pm <= 8.0f)) {
                float d = fmaxf(pm, 0.0f);      // per-lane shift (q = prow)
                float sc0 = exp2f(-d);
                mrun += d;
#pragma unroll
                for (int f = 0; f < 4; f++)
#pragma unroll
                    for (int r = 0; r < 4; r++) st[f][r] -= d;
#pragma unroll
                for (int r = 0; r < 4; r++) {
                    float so = __shfl(sc0, lg * 4 + r);
#pragma unroll
                    for (int f = 0; f < 4; f++) oacc[f][r] *= so;
                    acc5[r] *= so;
                }
            }

            // exp2 (no subtraction: st already max-shifted)
#pragma unroll
            for (int f = 0; f < 4; f++)
#pragma unroll
                for (int r = 0; r < 4; r++)
                    st[f][r] = exp2f(st[f][r]);

            // P -> Ps (wave-private rows; in-wave LDS ordering guards reuse)
            {
                const int halfoff = (lg & 1) << 2;
                const int cbase = lg >> 1;
#pragma unroll
                for (int f = 0; f < 4; f++) {
                    uint2 pw;
                    pw.x = cvt_pk_bf16(st[f][0], st[f][1]);
                    pw.y = cvt_pk_bf16(st[f][2], st[f][3]);
                    *(uint2*)(pbase + (((2 * f + cbase) ^ l7) << 3) + halfoff) = pw;
                }
            }

            // O += P V ; l += P * ones (acc5 in oacc register layout)
            __builtin_amdgcn_s_setprio(1);
#pragma unroll
            for (int ks = 0; ks < 2; ++ks) {
                bf16x8 pa = lds_frag(prd + (((ks * 4 + lg) ^ l7) << 3));
#pragma unroll
                for (int f = 0; f < 4; f++) {
                    bf16x8 vb = lds_frag(&Vs[cur][(f * 16 + l15) * 64 + (((ks * 4 + lg) ^ l7) << 3)]);
                    oacc[f] = __builtin_amdgcn_mfma_f32_16x16x32_bf16(pa, vb, oacc[f], 0, 0, 0);
                }
                acc5 = __builtin_amdgcn_mfma_f32_16x16x32_bf16(pa, vones, acc5, 0, 0, 0);
            }
            __builtin_amdgcn_s_setprio(0);
        };

        if (kt <= p) PROC(qA0, qA1, oaccA, accA5, mA, kt == p);
        PROC(qB0, qB1, oaccB, accB5, mB, kt == ktmax);

        __syncthreads();
    }

    const int b = bh >> 4, h = bh & 15;
#pragma unroll
    for (int r = 0; r < 4; r++) {
        float invA = 1.0f / accA5[r];
        int sgA = p * 64 + qrow0 + lg * 4 + r;
        unsigned short* orowA = Ow + ((size_t)(b * SEQ + sgA) * DMODEL) + h * 64 + l15;
#pragma unroll
        for (int f = 0; f < 4; f++) orowA[f * 16] = f2bf(oaccA[f][r] * invA);

        float invB = 1.0f / accB5[r];
        int sgB = qbB * 64 + qrow0 + lg * 4 + r;
        unsigned short* orowB = Ow + ((size_t)(b * SEQ + sgB) * DMODEL) + h * 64 + l15;
#pragma unroll
        for (int f = 0; f < 4; f++) orowB[f * 16] = f2bf(oaccB[f][r] * invB);
    }
}

extern "C" void kernel_launch(void* const* d_in, const int* in_sizes, int n_in,
                              void* d_out, int out_size, void* d_ws, size_t ws_size,
                              hipStream_t stream) {
    const float* x  = (const float*)d_in[0];
    const float* wq = (const float*)d_in[1];
    const float* wk = (const float*)d_in[2];
    const float* wv = (const float*)d_in[3];
    const float* wo = (const float*)d_in[4];

    unsigned short* ws = (unsigned short*)d_ws;
    const size_t MEL = (size_t)8192 * 1024;   // 8M elements
    const size_t WEL = (size_t)1024 * 1024;   // 1M elements
    unsigned short* xb  = ws;
    unsigned short* wqb = xb + MEL;           // 4 weights contiguous: wq|wk|wv|wo
    unsigned short* wob = wqb + 3 * WEL;
    unsigned short* qw  = wob + WEL;
    unsigned short* kw  = qw + MEL;
    unsigned short* vw  = kw + MEL;
    unsigned short* ow  = vw + MEL;

    cvt_all<<<12288, 256, 0, stream>>>(x, wq, wk, wv, wo, xb, wqb);

    gemm_qkv<<<dim3(24, 64), 256, 0, stream>>>(xb, wqb, qw, kw, vw);

    flash_attn<<<1024, 256, 0, stream>>>(qw, kw, vw, ow);

    gemm_out<<<512, 256, 0, stream>>>(ow, wob, (float*)d_out);
}

// Round 16
// 164.946 us; speedup vs baseline: 1.0855x; 1.0727x over previous
//
#include <hip/hip_runtime.h>
#include <stdint.h>

#define NHEAD  16
#define SEQ    2048
#define DMODEL 1024
#define BATCH  4

typedef __attribute__((ext_vector_type(4))) float f32x4;
typedef __attribute__((ext_vector_type(8))) __bf16 bf16x8;
typedef __attribute__((ext_vector_type(8))) unsigned short u16x8;

__device__ __forceinline__ unsigned short f2bf(float f) {
    unsigned int u = __builtin_bit_cast(unsigned int, f);
    u += 0x7FFFu + ((u >> 16) & 1u);   // RNE
    return (unsigned short)(u >> 16);
}

__device__ __forceinline__ unsigned int cvt_pk_bf16(float lo, float hi) {
    unsigned int r;
    asm("v_cvt_pk_bf16_f32 %0, %1, %2" : "=v"(r) : "v"(lo), "v"(hi));
    return r;
}

__device__ __forceinline__ float max3f(float a, float b, float c) {
    float d;
    asm("v_max3_f32 %0, %1, %2, %3" : "=v"(d) : "v"(a), "v"(b), "v"(c));
    return d;
}

// single-instruction v_exp_f32 (libm exp2f is ~20 VALU ops without fast-math)
__device__ __forceinline__ float fexp2(float x) {
    return __builtin_amdgcn_exp2f(x);
}

// async global->LDS, 16B per lane. LDS dest must be wave-uniform base + lane*16.
__device__ __forceinline__ void gload_lds16(const void* g, void* l) {
    __builtin_amdgcn_global_load_lds(
        (const __attribute__((address_space(1))) unsigned int*)(uintptr_t)g,
        (__attribute__((address_space(3))) unsigned int*)(uintptr_t)l,
        16, 0, 0);
}

__device__ __forceinline__ bf16x8 lds_frag(const unsigned short* p) {
    return __builtin_bit_cast(bf16x8, *(const u16x8*)p);
}

__device__ __forceinline__ bf16x8 gfrag(const unsigned short* p) {
    return __builtin_bit_cast(bf16x8, *(const u16x8*)p);
}

// ---------------- fused fp32 -> bf16 conversion (x + 4 weights, one launch) ----------------
__global__ __launch_bounds__(256) void cvt_all(const float* __restrict__ x,
                                               const float* __restrict__ w0,
                                               const float* __restrict__ w1,
                                               const float* __restrict__ w2,
                                               const float* __restrict__ w3,
                                               unsigned short* __restrict__ xb,
                                               unsigned short* __restrict__ wdst) {
    int b = blockIdx.x;
    const float* src;
    unsigned short* dst;
    int i;
    if (b < 8192) {
        src = x; dst = xb;
        i = b * 256 + threadIdx.x;
    } else {
        int wb = b - 8192;
        int which = wb >> 10;
        src = which == 0 ? w0 : which == 1 ? w1 : which == 2 ? w2 : w3;
        dst = wdst + (size_t)which * 1024 * 1024;
        i = (wb & 1023) * 256 + threadIdx.x;
    }
    float4 v = ((const float4*)src)[i];
    ushort4 o;
    o.x = f2bf(v.x); o.y = f2bf(v.y); o.z = f2bf(v.z); o.w = f2bf(v.w);
    ((ushort4*)dst)[i] = o;
}

// ---------------- fused QKV GEMM: [Q|K|V] = X(8192x1024) * Wcat(3072x1024)^T ----------------
// grid (24, 64): x = n-tile (0-7 Q, 8-15 K, 16-23 V), y = m-tile
// Q output is pre-scaled by 1/8*log2(e) so flash softmax works directly in log2 domain.
__global__ __launch_bounds__(256) void gemm_qkv(const unsigned short* __restrict__ A,
                                                const unsigned short* __restrict__ Wc,
                                                unsigned short* __restrict__ qw,
                                                unsigned short* __restrict__ kw,
                                                unsigned short* __restrict__ vw) {
    __shared__ __align__(16) unsigned short As[2][128 * 64];
    __shared__ __align__(16) unsigned short Bs[2][128 * 64];

    const int tid  = threadIdx.x;
    const int lane = tid & 63;
    const int wid  = tid >> 6;
    const int wm = wid >> 1, wn = wid & 1;
    const int l15 = lane & 15, lg = lane >> 4;

    const int tn = blockIdx.x;
    const int m0 = blockIdx.y * 128, n0 = tn * 128;

    f32x4 acc[4][4];
#pragma unroll
    for (int i = 0; i < 4; i++)
#pragma unroll
        for (int j = 0; j < 4; j++) acc[i][j] = f32x4{0.f, 0.f, 0.f, 0.f};

    const int e0 = tid * 8;
    auto STAGE = [&](int kk, int bufi) {
#pragma unroll
        for (int is = 0; is < 4; ++is) {
            int e = is * 2048 + e0;
            int row = e >> 6, col = e & 63;
            gload_lds16(A  + (size_t)(m0 + row) * 1024 + kk + col, &As[bufi][e]);
            gload_lds16(Wc + (size_t)(n0 + row) * 1024 + kk + col, &Bs[bufi][e]);
        }
    };

    STAGE(0, 0);
    __syncthreads();

    for (int kk = 0; kk < 1024; kk += 64) {
        const int cur = (kk >> 6) & 1;
        if (kk + 64 < 1024) STAGE(kk + 64, cur ^ 1);
#pragma unroll
        for (int ks = 0; ks < 2; ++ks) {
            bf16x8 a[4], b[4];
#pragma unroll
            for (int f = 0; f < 4; f++) {
                a[f] = lds_frag(&As[cur][(wm * 64 + f * 16 + l15) * 64 + ks * 32 + lg * 8]);
                b[f] = lds_frag(&Bs[cur][(wn * 64 + f * 16 + l15) * 64 + ks * 32 + lg * 8]);
            }
#pragma unroll
            for (int i = 0; i < 4; i++)
#pragma unroll
                for (int j = 0; j < 4; j++)
                    acc[i][j] = __builtin_amdgcn_mfma_f32_16x16x32_bf16(a[i], b[j], acc[i][j], 0, 0, 0);
        }
        __syncthreads();
    }

    if (tn >= 16) {   // V -> (b,h,dk,s) transposed
        unsigned short* out = vw;
#pragma unroll
        for (int i = 0; i < 4; i++)
#pragma unroll
            for (int r = 0; r < 4; r++) {
                int m = m0 + wm * 64 + i * 16 + lg * 4 + r;
                int b = m >> 11, s = m & 2047;
#pragma unroll
                for (int j = 0; j < 4; j++) {
                    int n = n0 + wn * 64 + j * 16 + l15;
                    int h = (n >> 6) & 15, dk = n & 63;
                    out[((size_t)(b * NHEAD + h) * 64 + dk) * SEQ + s] = f2bf(acc[i][j][r]);
                }
            }
    } else {          // Q or K with RoPE -> (b,h,s,dk)
        unsigned short* out = (tn < 8) ? qw : kw;
        const float qscale = (tn < 8) ? 0.18033688011112042f : 1.0f;   // 1/8*log2(e) for Q
        const float L2T = 13.287712379549449f;   // log2(10000)
        float invf[4];
#pragma unroll
        for (int j = 0; j < 4; j++) {
            int idx = j * 16 + l15;          // n % 64
            int t = idx >> 1;
            invf[j] = fexp2(-((float)(2 * t) * (1.0f / 64.0f)) * L2T);
        }
        const int par = l15 & 1;
#pragma unroll
        for (int i = 0; i < 4; i++)
#pragma unroll
            for (int r = 0; r < 4; r++) {
                int m = m0 + wm * 64 + i * 16 + lg * 4 + r;
                int b = m >> 11, s = m & 2047;
                float fs = (float)s;
#pragma unroll
                for (int j = 0; j < 4; j++) {
                    float v = acc[i][j][r];
                    float other = __shfl_xor(v, 1);
                    float sn, cs;
                    __sincosf(fs * invf[j], &sn, &cs);
                    float y = par ? fmaf(v, cs, other * sn) : fmaf(v, cs, -other * sn);
                    y *= qscale;
                    int n = n0 + wn * 64 + j * 16 + l15;
                    int h = (n >> 6) & 15, dk = n & 63;
                    out[((size_t)(b * NHEAD + h) * SEQ + s) * 64 + dk] = f2bf(y);
                }
            }
    }
}

// ---------------- output GEMM: d_out = OW(8192x1024) * Wo(1024x1024)^T, fp32 out ----------------
__global__ __launch_bounds__(256) void gemm_out(const unsigned short* __restrict__ A,
                                                const unsigned short* __restrict__ W,
                                                float* __restrict__ out) {
    __shared__ __align__(16) unsigned short As[2][128 * 64];
    __shared__ __align__(16) unsigned short Bs[2][128 * 64];

    const int tid  = threadIdx.x;
    const int lane = tid & 63;
    const int wid  = tid >> 6;
    const int wm = wid >> 1, wn = wid & 1;
    const int l15 = lane & 15, lg = lane >> 4;

    const int tn = blockIdx.x & 7;
    const int tm = blockIdx.x >> 3;
    const int m0 = tm * 128, n0 = tn * 128;

    f32x4 acc[4][4];
#pragma unroll
    for (int i = 0; i < 4; i++)
#pragma unroll
        for (int j = 0; j < 4; j++) acc[i][j] = f32x4{0.f, 0.f, 0.f, 0.f};

    const int e0 = tid * 8;
    auto STAGE = [&](int kk, int bufi) {
#pragma unroll
        for (int is = 0; is < 4; ++is) {
            int e = is * 2048 + e0;
            int row = e >> 6, col = e & 63;
            gload_lds16(A + (size_t)(m0 + row) * 1024 + kk + col, &As[bufi][e]);
            gload_lds16(W + (size_t)(n0 + row) * 1024 + kk + col, &Bs[bufi][e]);
        }
    };

    STAGE(0, 0);
    __syncthreads();

    for (int kk = 0; kk < 1024; kk += 64) {
        const int cur = (kk >> 6) & 1;
        if (kk + 64 < 1024) STAGE(kk + 64, cur ^ 1);
#pragma unroll
        for (int ks = 0; ks < 2; ++ks) {
            bf16x8 a[4], b[4];
#pragma unroll
            for (int f = 0; f < 4; f++) {
                a[f] = lds_frag(&As[cur][(wm * 64 + f * 16 + l15) * 64 + ks * 32 + lg * 8]);
                b[f] = lds_frag(&Bs[cur][(wn * 64 + f * 16 + l15) * 64 + ks * 32 + lg * 8]);
            }
#pragma unroll
            for (int i = 0; i < 4; i++)
#pragma unroll
                for (int j = 0; j < 4; j++)
                    acc[i][j] = __builtin_amdgcn_mfma_f32_16x16x32_bf16(a[i], b[j], acc[i][j], 0, 0, 0);
        }
        __syncthreads();
    }

#pragma unroll
    for (int i = 0; i < 4; i++)
#pragma unroll
        for (int r = 0; r < 4; r++) {
            int m = m0 + wm * 64 + i * 16 + lg * 4 + r;
            float* orow = out + (size_t)m * 1024 + n0 + wn * 64 + l15;
#pragma unroll
            for (int j = 0; j < 4; j++) orow[j * 16] = acc[i][j][r];
        }
}

// ---------------- causal flash attention: balanced pairing (tile p + tile 31-p) ----------------
// Q,K in (bh, s, dk) (Q pre-scaled by 1/8*log2e); V in (bh, dk, s). Out (b,s,dmodel) bf16.
// QK^T MFMA C-operand initialized to -mrun (scores come out max-shifted); exp2 via raw
// v_exp_f32 (libm exp2f is ~20 VALU ops at -O3 without fast-math — the hidden VALU elephant).
// Row-sum l via ones-MFMA (acc5); alternating-perm p remap for iteration balance.
__global__ __launch_bounds__(256, 4) void flash_attn(const unsigned short* __restrict__ Qw,
                                                     const unsigned short* __restrict__ Kw,
                                                     const unsigned short* __restrict__ Vw,
                                                     unsigned short* __restrict__ Ow) {
    __shared__ __align__(16) unsigned short Ks[2][64 * 64];
    __shared__ __align__(16) unsigned short Vs[2][64 * 64];   // [dk][kv]
    __shared__ __align__(16) unsigned short Ps[64 * 64];      // [q][kv], swizzled, reused A/B

    const int tid  = threadIdx.x;
    const int lane = tid & 63;
    const int w    = tid >> 6;
    const int l15 = lane & 15, lg = lane >> 4;
    const int l7 = l15 & 7;

    const int logical = (blockIdx.x & 7) * 128 + (blockIdx.x >> 3);
    const int bh = logical >> 4;
    const int idx = logical & 15;
    const int g = (logical >> 5) & 15;
    const int j = (idx + g) & 15;
    const int p = (j & 1) ? (15 - (j >> 1)) : (j >> 1);   // pair: q-tiles p and 31-p
    const int qbB = 31 - p;
    const int ktmax = qbB;

    const unsigned short* Kbh = Kw + (size_t)bh * (SEQ * 64);
    const unsigned short* Vbh = Vw + (size_t)bh * (64 * SEQ);

    const int qrow0 = w * 16;
    const int prow  = qrow0 + l15;

    const unsigned short* QrowA = Qw + (size_t)bh * (SEQ * 64) + (size_t)(p * 64 + prow) * 64;
    const unsigned short* QrowB = Qw + (size_t)bh * (SEQ * 64) + (size_t)(qbB * 64 + prow) * 64;
    bf16x8 qA0 = gfrag(QrowA + lg * 8), qA1 = gfrag(QrowA + 32 + lg * 8);
    bf16x8 qB0 = gfrag(QrowB + lg * 8), qB1 = gfrag(QrowB + 32 + lg * 8);

    u16x8 onesu = {0x3F80, 0x3F80, 0x3F80, 0x3F80, 0x3F80, 0x3F80, 0x3F80, 0x3F80};
    const bf16x8 vones = __builtin_bit_cast(bf16x8, onesu);   // bf16 1.0 x8

    auto STAGE = [&](int kt2, int bufi) {
#pragma unroll
        for (int is = 0; is < 2; ++is) {
            int e = (is * 256 + tid) * 8;
            int row = e >> 6, c = (e >> 3) & 7;
            int sc = (c ^ (row & 7)) << 3;
            gload_lds16(Kbh + (size_t)kt2 * 4096 + row * 64 + sc, &Ks[bufi][e]);
            gload_lds16(Vbh + (size_t)row * SEQ + kt2 * 64 + sc, &Vs[bufi][e]);
        }
    };

    STAGE(0, 0);

    f32x4 oaccA[4], oaccB[4];
#pragma unroll
    for (int f = 0; f < 4; f++) { oaccA[f] = f32x4{0.f, 0.f, 0.f, 0.f}; oaccB[f] = f32x4{0.f, 0.f, 0.f, 0.f}; }
    f32x4 accA5 = f32x4{0.f, 0.f, 0.f, 0.f}, accB5 = f32x4{0.f, 0.f, 0.f, 0.f};   // row-sums l
    float mA = 0.f, mB = 0.f;   // running max (log2 domain), relative-shift tracked via C-init

    unsigned short* pbase = &Ps[prow * 64];
    const unsigned short* prd = &Ps[prow * 64];

    __syncthreads();

    for (int kt = 0; kt <= ktmax; ++kt) {
        const int cur = kt & 1;
        if (kt < ktmax) STAGE(kt + 1, cur ^ 1);

        auto PROC = [&](bf16x8 q0, bf16x8 q1, f32x4* oacc, f32x4& acc5, float& mrun, bool diag) {
            // S^T = K·Q with C init = -mrun: st = S - mrun directly out of the MFMA
            f32x4 st[4];
            const f32x4 cinit = {-mrun, -mrun, -mrun, -mrun};
            __builtin_amdgcn_s_setprio(1);
#pragma unroll
            for (int f = 0; f < 4; f++) {
                bf16x8 kfrag = lds_frag(&Ks[cur][(f * 16 + l15) * 64 + ((lg ^ l7) << 3)]);
                st[f] = __builtin_amdgcn_mfma_f32_16x16x32_bf16(kfrag, q0, cinit, 0, 0, 0);
            }
#pragma unroll
            for (int f = 0; f < 4; f++) {
                bf16x8 kfrag = lds_frag(&Ks[cur][(f * 16 + l15) * 64 + (((4 + lg) ^ l7) << 3)]);
                st[f] = __builtin_amdgcn_mfma_f32_16x16x32_bf16(kfrag, q1, st[f], 0, 0, 0);
            }
            __builtin_amdgcn_s_setprio(0);

            if (diag) {
#pragma unroll
                for (int f = 0; f < 4; f++)
#pragma unroll
                    for (int r = 0; r < 4; r++) {
                        int kv = f * 16 + 4 * lg + r;
                        if (kv > prow) st[f][r] = -3.0e38f;
                    }
            }

            // per-q max of (S - mrun): 7 max3 + 1 fmax in-lane, then 2 shuffles
            float m1 = max3f(st[0][0], st[0][1], st[0][2]);
            float m2 = max3f(st[0][3], st[1][0], st[1][1]);
            float m3 = max3f(st[1][2], st[1][3], st[2][0]);
            float m4 = max3f(st[2][1], st[2][2], st[2][3]);
            float m5 = max3f(st[3][0], st[3][1], st[3][2]);
            float pm = fmaxf(max3f(m1, m2, m3), max3f(m4, m5, st[3][3]));
            pm = fmaxf(pm, __shfl_xor(pm, 16));
            pm = fmaxf(pm, __shfl_xor(pm, 32));

            // defer-max (T13): rescale only when some row grew by > 8 over mrun
            if (!__all(pm <= 8.0f)) {
                float d = fmaxf(pm, 0.0f);      // per-lane shift (q = prow)
                float sc0 = fexp2(-d);
                mrun += d;
#pragma unroll
                for (int f = 0; f < 4; f++)
#pragma unroll
                    for (int r = 0; r < 4; r++) st[f][r] -= d;
#pragma unroll
                for (int r = 0; r < 4; r++) {
                    float so = __shfl(sc0, lg * 4 + r);
#pragma unroll
                    for (int f = 0; f < 4; f++) oacc[f][r] *= so;
                    acc5[r] *= so;
                }
            }

            // exp2 via single v_exp_f32 (st already max-shifted)
#pragma unroll
            for (int f = 0; f < 4; f++)
#pragma unroll
                for (int r = 0; r < 4; r++)
                    st[f][r] = fexp2(st[f][r]);

            // P -> Ps (wave-private rows; in-wave LDS ordering guards reuse)
            {
                const int halfoff = (lg & 1) << 2;
                const int cbase = lg >> 1;
#pragma unroll
                for (int f = 0; f < 4; f++) {
                    uint2 pw;
                    pw.x = cvt_pk_bf16(st[f][0], st[f][1]);
                    pw.y = cvt_pk_bf16(st[f][2], st[f][3]);
                    *(uint2*)(pbase + (((2 * f + cbase) ^ l7) << 3) + halfoff) = pw;
                }
            }

            // O += P V ; l += P * ones (acc5 in oacc register layout)
            __builtin_amdgcn_s_setprio(1);
#pragma unroll
            for (int ks = 0; ks < 2; ++ks) {
                bf16x8 pa = lds_frag(prd + (((ks * 4 + lg) ^ l7) << 3));
#pragma unroll
                for (int f = 0; f < 4; f++) {
                    bf16x8 vb = lds_frag(&Vs[cur][(f * 16 + l15) * 64 + (((ks * 4 + lg) ^ l7) << 3)]);
                    oacc[f] = __builtin_amdgcn_mfma_f32_16x16x32_bf16(pa, vb, oacc[f], 0, 0, 0);
                }
                acc5 = __builtin_amdgcn_mfma_f32_16x16x32_bf16(pa, vones, acc5, 0, 0, 0);
            }
            __builtin_amdgcn_s_setprio(0);
        };

        if (kt <= p) PROC(qA0, qA1, oaccA, accA5, mA, kt == p);
        PROC(qB0, qB1, oaccB, accB5, mB, kt == ktmax);

        __syncthreads();
    }

    const int b = bh >> 4, h = bh & 15;
#pragma unroll
    for (int r = 0; r < 4; r++) {
        float invA = 1.0f / accA5[r];
        int sgA = p * 64 + qrow0 + lg * 4 + r;
        unsigned short* orowA = Ow + ((size_t)(b * SEQ + sgA) * DMODEL) + h * 64 + l15;
#pragma unroll
        for (int f = 0; f < 4; f++) orowA[f * 16] = f2bf(oaccA[f][r] * invA);

        float invB = 1.0f / accB5[r];
        int sgB = qbB * 64 + qrow0 + lg * 4 + r;
        unsigned short* orowB = Ow + ((size_t)(b * SEQ + sgB) * DMODEL) + h * 64 + l15;
#pragma unroll
        for (int f = 0; f < 4; f++) orowB[f * 16] = f2bf(oaccB[f][r] * invB);
    }
}

extern "C" void kernel_launch(void* const* d_in, const int* in_sizes, int n_in,
                              void* d_out, int out_size, void* d_ws, size_t ws_size,
                              hipStream_t stream) {
    const float* x  = (const float*)d_in[0];
    const float* wq = (const float*)d_in[1];
    const float* wk = (const float*)d_in[2];
    const float* wv = (const float*)d_in[3];
    const float* wo = (const float*)d_in[4];

    unsigned short* ws = (unsigned short*)d_ws;
    const size_t MEL = (size_t)8192 * 1024;   // 8M elements
    const size_t WEL = (size_t)1024 * 1024;   // 1M elements
    unsigned short* xb  = ws;
    unsigned short* wqb = xb + MEL;           // 4 weights contiguous: wq|wk|wv|wo
    unsigned short* wob = wqb + 3 * WEL;
    unsigned short* qw  = wob + WEL;
    unsigned short* kw  = qw + MEL;
    unsigned short* vw  = kw + MEL;
    unsigned short* ow  = vw + MEL;

    cvt_all<<<12288, 256, 0, stream>>>(x, wq, wk, wv, wo, xb, wqb);

    gemm_qkv<<<dim3(24, 64), 256, 0, stream>>>(xb, wqb, qw, kw, vw);

    flash_attn<<<1024, 256, 0, stream>>>(qw, kw, vw, ow);

    gemm_out<<<512, 256, 0, stream>>>(ow, wob, (float*)d_out);
}

// Round 17
// 156.344 us; speedup vs baseline: 1.1452x; 1.0550x over previous
//
#include <hip/hip_runtime.h>
#include <stdint.h>

#define NHEAD  16
#define SEQ    2048
#define DMODEL 1024
#define BATCH  4

typedef __attribute__((ext_vector_type(4))) float f32x4;
typedef __attribute__((ext_vector_type(8))) __bf16 bf16x8;
typedef __attribute__((ext_vector_type(8))) unsigned short u16x8;

__device__ __forceinline__ unsigned short f2bf(float f) {
    unsigned int u = __builtin_bit_cast(unsigned int, f);
    u += 0x7FFFu + ((u >> 16) & 1u);   // RNE
    return (unsigned short)(u >> 16);
}

__device__ __forceinline__ unsigned int cvt_pk_bf16(float lo, float hi) {
    unsigned int r;
    asm("v_cvt_pk_bf16_f32 %0, %1, %2" : "=v"(r) : "v"(lo), "v"(hi));
    return r;
}

__device__ __forceinline__ float max3f(float a, float b, float c) {
    float d;
    asm("v_max3_f32 %0, %1, %2, %3" : "=v"(d) : "v"(a), "v"(b), "v"(c));
    return d;
}

// single-instruction v_exp_f32 (libm exp2f is ~20 VALU ops without fast-math)
__device__ __forceinline__ float fexp2(float x) {
    return __builtin_amdgcn_exp2f(x);
}

// async global->LDS, 16B per lane. LDS dest must be wave-uniform base + lane*16.
__device__ __forceinline__ void gload_lds16(const void* g, void* l) {
    __builtin_amdgcn_global_load_lds(
        (const __attribute__((address_space(1))) unsigned int*)(uintptr_t)g,
        (__attribute__((address_space(3))) unsigned int*)(uintptr_t)l,
        16, 0, 0);
}

__device__ __forceinline__ bf16x8 lds_frag(const unsigned short* p) {
    return __builtin_bit_cast(bf16x8, *(const u16x8*)p);
}

__device__ __forceinline__ bf16x8 gfrag(const unsigned short* p) {
    return __builtin_bit_cast(bf16x8, *(const u16x8*)p);
}

// ---------------- fused fp32 -> bf16 conversion (x + 4 weights, one launch) ----------------
__global__ __launch_bounds__(256) void cvt_all(const float* __restrict__ x,
                                               const float* __restrict__ w0,
                                               const float* __restrict__ w1,
                                               const float* __restrict__ w2,
                                               const float* __restrict__ w3,
                                               unsigned short* __restrict__ xb,
                                               unsigned short* __restrict__ wdst) {
    int b = blockIdx.x;
    const float* src;
    unsigned short* dst;
    int i;
    if (b < 8192) {
        src = x; dst = xb;
        i = b * 256 + threadIdx.x;
    } else {
        int wb = b - 8192;
        int which = wb >> 10;
        src = which == 0 ? w0 : which == 1 ? w1 : which == 2 ? w2 : w3;
        dst = wdst + (size_t)which * 1024 * 1024;
        i = (wb & 1023) * 256 + threadIdx.x;
    }
    float4 v = ((const float4*)src)[i];
    ushort4 o;
    o.x = f2bf(v.x); o.y = f2bf(v.y); o.z = f2bf(v.z); o.w = f2bf(v.w);
    ((ushort4*)dst)[i] = o;
}

// ---------------- fused QKV GEMM: [Q|K|V] = X(8192x1024) * Wcat(3072x1024)^T ----------------
// grid (24, 64): x = n-tile (0-7 Q, 8-15 K, 16-23 V), y = m-tile
// Q output is pre-scaled by 1/8*log2(e) so flash softmax works directly in log2 domain.
// LDS chunk-XOR swizzled (chunk c of row r stored at c^(r&7); pre-swizzled global source):
// kills the 16-way ds_read_b128 bank conflict (1.9e7/dispatch measured unswizzled).
__global__ __launch_bounds__(256) void gemm_qkv(const unsigned short* __restrict__ A,
                                                const unsigned short* __restrict__ Wc,
                                                unsigned short* __restrict__ qw,
                                                unsigned short* __restrict__ kw,
                                                unsigned short* __restrict__ vw) {
    __shared__ __align__(16) unsigned short As[2][128 * 64];
    __shared__ __align__(16) unsigned short Bs[2][128 * 64];

    const int tid  = threadIdx.x;
    const int lane = tid & 63;
    const int wid  = tid >> 6;
    const int wm = wid >> 1, wn = wid & 1;
    const int l15 = lane & 15, lg = lane >> 4;
    const int l7 = l15 & 7;

    const int tn = blockIdx.x;
    const int m0 = blockIdx.y * 128, n0 = tn * 128;

    f32x4 acc[4][4];
#pragma unroll
    for (int i = 0; i < 4; i++)
#pragma unroll
        for (int j = 0; j < 4; j++) acc[i][j] = f32x4{0.f, 0.f, 0.f, 0.f};

    const int e0 = tid * 8;
    auto STAGE = [&](int kk, int bufi) {
#pragma unroll
        for (int is = 0; is < 4; ++is) {
            int e = is * 2048 + e0;
            int row = e >> 6, c = (e >> 3) & 7;
            int col = (c ^ (row & 7)) << 3;
            gload_lds16(A  + (size_t)(m0 + row) * 1024 + kk + col, &As[bufi][e]);
            gload_lds16(Wc + (size_t)(n0 + row) * 1024 + kk + col, &Bs[bufi][e]);
        }
    };

    STAGE(0, 0);
    __syncthreads();

    for (int kk = 0; kk < 1024; kk += 64) {
        const int cur = (kk >> 6) & 1;
        if (kk + 64 < 1024) STAGE(kk + 64, cur ^ 1);
#pragma unroll
        for (int ks = 0; ks < 2; ++ks) {
            const int cso = ((ks * 4 + lg) ^ l7) << 3;   // swizzled chunk offset
            bf16x8 a[4], b[4];
#pragma unroll
            for (int f = 0; f < 4; f++) {
                a[f] = lds_frag(&As[cur][(wm * 64 + f * 16 + l15) * 64 + cso]);
                b[f] = lds_frag(&Bs[cur][(wn * 64 + f * 16 + l15) * 64 + cso]);
            }
#pragma unroll
            for (int i = 0; i < 4; i++)
#pragma unroll
                for (int j = 0; j < 4; j++)
                    acc[i][j] = __builtin_amdgcn_mfma_f32_16x16x32_bf16(a[i], b[j], acc[i][j], 0, 0, 0);
        }
        __syncthreads();
    }

    if (tn >= 16) {   // V -> (b,h,dk,s) transposed
        unsigned short* out = vw;
#pragma unroll
        for (int i = 0; i < 4; i++)
#pragma unroll
            for (int r = 0; r < 4; r++) {
                int m = m0 + wm * 64 + i * 16 + lg * 4 + r;
                int b = m >> 11, s = m & 2047;
#pragma unroll
                for (int j = 0; j < 4; j++) {
                    int n = n0 + wn * 64 + j * 16 + l15;
                    int h = (n >> 6) & 15, dk = n & 63;
                    out[((size_t)(b * NHEAD + h) * 64 + dk) * SEQ + s] = f2bf(acc[i][j][r]);
                }
            }
    } else {          // Q or K with RoPE -> (b,h,s,dk)
        unsigned short* out = (tn < 8) ? qw : kw;
        const float qscale = (tn < 8) ? 0.18033688011112042f : 1.0f;   // 1/8*log2(e) for Q
        const float L2T = 13.287712379549449f;   // log2(10000)
        float invf[4];
#pragma unroll
        for (int j = 0; j < 4; j++) {
            int idx = j * 16 + l15;          // n % 64
            int t = idx >> 1;
            invf[j] = fexp2(-((float)(2 * t) * (1.0f / 64.0f)) * L2T);
        }
        const int par = l15 & 1;
#pragma unroll
        for (int i = 0; i < 4; i++)
#pragma unroll
            for (int r = 0; r < 4; r++) {
                int m = m0 + wm * 64 + i * 16 + lg * 4 + r;
                int b = m >> 11, s = m & 2047;
                float fs = (float)s;
#pragma unroll
                for (int j = 0; j < 4; j++) {
                    float v = acc[i][j][r];
                    float other = __shfl_xor(v, 1);
                    float sn, cs;
                    __sincosf(fs * invf[j], &sn, &cs);
                    float y = par ? fmaf(v, cs, other * sn) : fmaf(v, cs, -other * sn);
                    y *= qscale;
                    int n = n0 + wn * 64 + j * 16 + l15;
                    int h = (n >> 6) & 15, dk = n & 63;
                    out[((size_t)(b * NHEAD + h) * SEQ + s) * 64 + dk] = f2bf(y);
                }
            }
    }
}

// ---------------- output GEMM: d_out = OW(8192x1024) * Wo(1024x1024)^T, fp32 out ----------------
__global__ __launch_bounds__(256) void gemm_out(const unsigned short* __restrict__ A,
                                                const unsigned short* __restrict__ W,
                                                float* __restrict__ out) {
    __shared__ __align__(16) unsigned short As[2][128 * 64];
    __shared__ __align__(16) unsigned short Bs[2][128 * 64];

    const int tid  = threadIdx.x;
    const int lane = tid & 63;
    const int wid  = tid >> 6;
    const int wm = wid >> 1, wn = wid & 1;
    const int l15 = lane & 15, lg = lane >> 4;
    const int l7 = l15 & 7;

    const int tn = blockIdx.x & 7;
    const int tm = blockIdx.x >> 3;
    const int m0 = tm * 128, n0 = tn * 128;

    f32x4 acc[4][4];
#pragma unroll
    for (int i = 0; i < 4; i++)
#pragma unroll
        for (int j = 0; j < 4; j++) acc[i][j] = f32x4{0.f, 0.f, 0.f, 0.f};

    const int e0 = tid * 8;
    auto STAGE = [&](int kk, int bufi) {
#pragma unroll
        for (int is = 0; is < 4; ++is) {
            int e = is * 2048 + e0;
            int row = e >> 6, c = (e >> 3) & 7;
            int col = (c ^ (row & 7)) << 3;
            gload_lds16(A + (size_t)(m0 + row) * 1024 + kk + col, &As[bufi][e]);
            gload_lds16(W + (size_t)(n0 + row) * 1024 + kk + col, &Bs[bufi][e]);
        }
    };

    STAGE(0, 0);
    __syncthreads();

    for (int kk = 0; kk < 1024; kk += 64) {
        const int cur = (kk >> 6) & 1;
        if (kk + 64 < 1024) STAGE(kk + 64, cur ^ 1);
#pragma unroll
        for (int ks = 0; ks < 2; ++ks) {
            const int cso = ((ks * 4 + lg) ^ l7) << 3;
            bf16x8 a[4], b[4];
#pragma unroll
            for (int f = 0; f < 4; f++) {
                a[f] = lds_frag(&As[cur][(wm * 64 + f * 16 + l15) * 64 + cso]);
                b[f] = lds_frag(&Bs[cur][(wn * 64 + f * 16 + l15) * 64 + cso]);
            }
#pragma unroll
            for (int i = 0; i < 4; i++)
#pragma unroll
                for (int j = 0; j < 4; j++)
                    acc[i][j] = __builtin_amdgcn_mfma_f32_16x16x32_bf16(a[i], b[j], acc[i][j], 0, 0, 0);
        }
        __syncthreads();
    }

#pragma unroll
    for (int i = 0; i < 4; i++)
#pragma unroll
        for (int r = 0; r < 4; r++) {
            int m = m0 + wm * 64 + i * 16 + lg * 4 + r;
            float* orow = out + (size_t)m * 1024 + n0 + wn * 64 + l15;
#pragma unroll
            for (int j = 0; j < 4; j++) orow[j * 16] = acc[i][j][r];
        }
}

// ---------------- causal flash attention: balanced pairing (tile p + tile 31-p) ----------------
// Q,K in (bh, s, dk) (Q pre-scaled by 1/8*log2e); V in (bh, dk, s). Out (b,s,dmodel) bf16.
// QK^T MFMA C-operand initialized to -mrun (scores come out max-shifted); exp2 via raw
// v_exp_f32. Row-sum l via ones-MFMA (acc5); alternating-perm p remap for iteration balance.
__global__ __launch_bounds__(256, 4) void flash_attn(const unsigned short* __restrict__ Qw,
                                                     const unsigned short* __restrict__ Kw,
                                                     const unsigned short* __restrict__ Vw,
                                                     unsigned short* __restrict__ Ow) {
    __shared__ __align__(16) unsigned short Ks[2][64 * 64];
    __shared__ __align__(16) unsigned short Vs[2][64 * 64];   // [dk][kv]
    __shared__ __align__(16) unsigned short Ps[64 * 64];      // [q][kv], swizzled, reused A/B

    const int tid  = threadIdx.x;
    const int lane = tid & 63;
    const int w    = tid >> 6;
    const int l15 = lane & 15, lg = lane >> 4;
    const int l7 = l15 & 7;

    const int logical = (blockIdx.x & 7) * 128 + (blockIdx.x >> 3);
    const int bh = logical >> 4;
    const int idx = logical & 15;
    const int g = (logical >> 5) & 15;
    const int j = (idx + g) & 15;
    const int p = (j & 1) ? (15 - (j >> 1)) : (j >> 1);   // pair: q-tiles p and 31-p
    const int qbB = 31 - p;
    const int ktmax = qbB;

    const unsigned short* Kbh = Kw + (size_t)bh * (SEQ * 64);
    const unsigned short* Vbh = Vw + (size_t)bh * (64 * SEQ);

    const int qrow0 = w * 16;
    const int prow  = qrow0 + l15;

    const unsigned short* QrowA = Qw + (size_t)bh * (SEQ * 64) + (size_t)(p * 64 + prow) * 64;
    const unsigned short* QrowB = Qw + (size_t)bh * (SEQ * 64) + (size_t)(qbB * 64 + prow) * 64;
    bf16x8 qA0 = gfrag(QrowA + lg * 8), qA1 = gfrag(QrowA + 32 + lg * 8);
    bf16x8 qB0 = gfrag(QrowB + lg * 8), qB1 = gfrag(QrowB + 32 + lg * 8);

    u16x8 onesu = {0x3F80, 0x3F80, 0x3F80, 0x3F80, 0x3F80, 0x3F80, 0x3F80, 0x3F80};
    const bf16x8 vones = __builtin_bit_cast(bf16x8, onesu);   // bf16 1.0 x8

    auto STAGE = [&](int kt2, int bufi) {
#pragma unroll
        for (int is = 0; is < 2; ++is) {
            int e = (is * 256 + tid) * 8;
            int row = e >> 6, c = (e >> 3) & 7;
            int sc = (c ^ (row & 7)) << 3;
            gload_lds16(Kbh + (size_t)kt2 * 4096 + row * 64 + sc, &Ks[bufi][e]);
            gload_lds16(Vbh + (size_t)row * SEQ + kt2 * 64 + sc, &Vs[bufi][e]);
        }
    };

    STAGE(0, 0);

    f32x4 oaccA[4], oaccB[4];
#pragma unroll
    for (int f = 0; f < 4; f++) { oaccA[f] = f32x4{0.f, 0.f, 0.f, 0.f}; oaccB[f] = f32x4{0.f, 0.f, 0.f, 0.f}; }
    f32x4 accA5 = f32x4{0.f, 0.f, 0.f, 0.f}, accB5 = f32x4{0.f, 0.f, 0.f, 0.f};   // row-sums l
    float mA = 0.f, mB = 0.f;   // running max (log2 domain), relative-shift tracked via C-init

    unsigned short* pbase = &Ps[prow * 64];
    const unsigned short* prd = &Ps[prow * 64];

    __syncthreads();

    for (int kt = 0; kt <= ktmax; ++kt) {
        const int cur = kt & 1;
        if (kt < ktmax) STAGE(kt + 1, cur ^ 1);

        auto PROC = [&](bf16x8 q0, bf16x8 q1, f32x4* oacc, f32x4& acc5, float& mrun, bool diag) {
            // S^T = K·Q with C init = -mrun: st = S - mrun directly out of the MFMA
            f32x4 st[4];
            const f32x4 cinit = {-mrun, -mrun, -mrun, -mrun};
            __builtin_amdgcn_s_setprio(1);
#pragma unroll
            for (int f = 0; f < 4; f++) {
                bf16x8 kfrag = lds_frag(&Ks[cur][(f * 16 + l15) * 64 + ((lg ^ l7) << 3)]);
                st[f] = __builtin_amdgcn_mfma_f32_16x16x32_bf16(kfrag, q0, cinit, 0, 0, 0);
            }
#pragma unroll
            for (int f = 0; f < 4; f++) {
                bf16x8 kfrag = lds_frag(&Ks[cur][(f * 16 + l15) * 64 + (((4 + lg) ^ l7) << 3)]);
                st[f] = __builtin_amdgcn_mfma_f32_16x16x32_bf16(kfrag, q1, st[f], 0, 0, 0);
            }
            __builtin_amdgcn_s_setprio(0);

            if (diag) {
#pragma unroll
                for (int f = 0; f < 4; f++)
#pragma unroll
                    for (int r = 0; r < 4; r++) {
                        int kv = f * 16 + 4 * lg + r;
                        if (kv > prow) st[f][r] = -3.0e38f;
                    }
            }

            // per-q max of (S - mrun): 7 max3 + 1 fmax in-lane, then 2 shuffles
            float m1 = max3f(st[0][0], st[0][1], st[0][2]);
            float m2 = max3f(st[0][3], st[1][0], st[1][1]);
            float m3 = max3f(st[1][2], st[1][3], st[2][0]);
            float m4 = max3f(st[2][1], st[2][2], st[2][3]);
            float m5 = max3f(st[3][0], st[3][1], st[3][2]);
            float pm = fmaxf(max3f(m1, m2, m3), max3f(m4, m5, st[3][3]));
            pm = fmaxf(pm, __shfl_xor(pm, 16));
            pm = fmaxf(pm, __shfl_xor(pm, 32));

            // defer-max (T13): rescale only when some row grew by > 8 over mrun
            if (!__all(pm <= 8.0f)) {
                float d = fmaxf(pm, 0.0f);      // per-lane shift (q = prow)
                float sc0 = fexp2(-d);
                mrun += d;
#pragma unroll
                for (int f = 0; f < 4; f++)
#pragma unroll
                    for (int r = 0; r < 4; r++) st[f][r] -= d;
#pragma unroll
                for (int r = 0; r < 4; r++) {
                    float so = __shfl(sc0, lg * 4 + r);
#pragma unroll
                    for (int f = 0; f < 4; f++) oacc[f][r] *= so;
                    acc5[r] *= so;
                }
            }

            // exp2 via single v_exp_f32 (st already max-shifted)
#pragma unroll
            for (int f = 0; f < 4; f++)
#pragma unroll
                for (int r = 0; r < 4; r++)
                    st[f][r] = fexp2(st[f][r]);

            // P -> Ps (wave-private rows; in-wave LDS ordering guards reuse)
            {
                const int halfoff = (lg & 1) << 2;
                const int cbase = lg >> 1;
#pragma unroll
                for (int f = 0; f < 4; f++) {
                    uint2 pw;
                    pw.x = cvt_pk_bf16(st[f][0], st[f][1]);
                    pw.y = cvt_pk_bf16(st[f][2], st[f][3]);
                    *(uint2*)(pbase + (((2 * f + cbase) ^ l7) << 3) + halfoff) = pw;
                }
            }

            // O += P V ; l += P * ones (acc5 in oacc register layout)
            __builtin_amdgcn_s_setprio(1);
#pragma unroll
            for (int ks = 0; ks < 2; ++ks) {
                bf16x8 pa = lds_frag(prd + (((ks * 4 + lg) ^ l7) << 3));
#pragma unroll
                for (int f = 0; f < 4; f++) {
                    bf16x8 vb = lds_frag(&Vs[cur][(f * 16 + l15) * 64 + (((ks * 4 + lg) ^ l7) << 3)]);
                    oacc[f] = __builtin_amdgcn_mfma_f32_16x16x32_bf16(pa, vb, oacc[f], 0, 0, 0);
                }
                acc5 = __builtin_amdgcn_mfma_f32_16x16x32_bf16(pa, vones, acc5, 0, 0, 0);
            }
            __builtin_amdgcn_s_setprio(0);
        };

        if (kt <= p) PROC(qA0, qA1, oaccA, accA5, mA, kt == p);
        PROC(qB0, qB1, oaccB, accB5, mB, kt == ktmax);

        __syncthreads();
    }

    const int b = bh >> 4, h = bh & 15;
#pragma unroll
    for (int r = 0; r < 4; r++) {
        float invA = 1.0f / accA5[r];
        int sgA = p * 64 + qrow0 + lg * 4 + r;
        unsigned short* orowA = Ow + ((size_t)(b * SEQ + sgA) * DMODEL) + h * 64 + l15;
#pragma unroll
        for (int f = 0; f < 4; f++) orowA[f * 16] = f2bf(oaccA[f][r] * invA);

        float invB = 1.0f / accB5[r];
        int sgB = qbB * 64 + qrow0 + lg * 4 + r;
        unsigned short* orowB = Ow + ((size_t)(b * SEQ + sgB) * DMODEL) + h * 64 + l15;
#pragma unroll
        for (int f = 0; f < 4; f++) orowB[f * 16] = f2bf(oaccB[f][r] * invB);
    }
}

extern "C" void kernel_launch(void* const* d_in, const int* in_sizes, int n_in,
                              void* d_out, int out_size, void* d_ws, size_t ws_size,
                              hipStream_t stream) {
    const float* x  = (const float*)d_in[0];
    const float* wq = (const float*)d_in[1];
    const float* wk = (const float*)d_in[2];
    const float* wv = (const float*)d_in[3];
    const float* wo = (const float*)d_in[4];

    unsigned short* ws = (unsigned short*)d_ws;
    const size_t MEL = (size_t)8192 * 1024;   // 8M elements
    const size_t WEL = (size_t)1024 * 1024;   // 1M elements
    unsigned short* xb  = ws;
    unsigned short* wqb = xb + MEL;           // 4 weights contiguous: wq|wk|wv|wo
    unsigned short* wob = wqb + 3 * WEL;
    unsigned short* qw  = wob + WEL;
    unsigned short* kw  = qw + MEL;
    unsigned short* vw  = kw + MEL;
    unsigned short* ow  = vw + MEL;

    cvt_all<<<12288, 256, 0, stream>>>(x, wq, wk, wv, wo, xb, wqb);

    gemm_qkv<<<dim3(24, 64), 256, 0, stream>>>(xb, wqb, qw, kw, vw);

    flash_attn<<<1024, 256, 0, stream>>>(qw, kw, vw, ow);

    gemm_out<<<512, 256, 0, stream>>>(ow, wob, (float*)d_out);
}

// Round 19
// 156.285 us; speedup vs baseline: 1.1456x; 1.0004x over previous
//
#include <hip/hip_runtime.h>
#include <stdint.h>

#define NHEAD  16
#define SEQ    2048
#define DMODEL 1024
#define BATCH  4

typedef __attribute__((ext_vector_type(4))) float f32x4;
typedef __attribute__((ext_vector_type(8))) __bf16 bf16x8;
typedef __attribute__((ext_vector_type(8))) unsigned short u16x8;

__device__ __forceinline__ unsigned short f2bf(float f) {
    unsigned int u = __builtin_bit_cast(unsigned int, f);
    u += 0x7FFFu + ((u >> 16) & 1u);   // RNE
    return (unsigned short)(u >> 16);
}

__device__ __forceinline__ unsigned int cvt_pk_bf16(float lo, float hi) {
    unsigned int r;
    asm("v_cvt_pk_bf16_f32 %0, %1, %2" : "=v"(r) : "v"(lo), "v"(hi));
    return r;
}

__device__ __forceinline__ float max3f(float a, float b, float c) {
    float d;
    asm("v_max3_f32 %0, %1, %2, %3" : "=v"(d) : "v"(a), "v"(b), "v"(c));
    return d;
}

// single-instruction v_exp_f32 (libm exp2f is ~20 VALU ops without fast-math)
__device__ __forceinline__ float fexp2(float x) {
    return __builtin_amdgcn_exp2f(x);
}

// async global->LDS, 16B per lane. LDS dest must be wave-uniform base + lane*16.
__device__ __forceinline__ void gload_lds16(const void* g, void* l) {
    __builtin_amdgcn_global_load_lds(
        (const __attribute__((address_space(1))) unsigned int*)(uintptr_t)g,
        (__attribute__((address_space(3))) unsigned int*)(uintptr_t)l,
        16, 0, 0);
}

__device__ __forceinline__ bf16x8 lds_frag(const unsigned short* p) {
    return __builtin_bit_cast(bf16x8, *(const u16x8*)p);
}

__device__ __forceinline__ bf16x8 gfrag(const unsigned short* p) {
    return __builtin_bit_cast(bf16x8, *(const u16x8*)p);
}

// ---------------- fused fp32 -> bf16 conversion (x + 4 weights, one launch) ----------------
__global__ __launch_bounds__(256) void cvt_all(const float* __restrict__ x,
                                               const float* __restrict__ w0,
                                               const float* __restrict__ w1,
                                               const float* __restrict__ w2,
                                               const float* __restrict__ w3,
                                               unsigned short* __restrict__ xb,
                                               unsigned short* __restrict__ wdst) {
    int b = blockIdx.x;
    const float* src;
    unsigned short* dst;
    int i;
    if (b < 8192) {
        src = x; dst = xb;
        i = b * 256 + threadIdx.x;
    } else {
        int wb = b - 8192;
        int which = wb >> 10;
        src = which == 0 ? w0 : which == 1 ? w1 : which == 2 ? w2 : w3;
        dst = wdst + (size_t)which * 1024 * 1024;
        i = (wb & 1023) * 256 + threadIdx.x;
    }
    float4 v = ((const float4*)src)[i];
    ushort4 o;
    o.x = f2bf(v.x); o.y = f2bf(v.y); o.z = f2bf(v.z); o.w = f2bf(v.w);
    ((ushort4*)dst)[i] = o;
}

// ---------------- fused QKV GEMM: [Q|K|V] = X(8192x1024) * Wcat(3072x1024)^T ----------------
// grid (24, 64): x = n-tile (0-7 Q, 8-15 K, 16-23 V), y = m-tile
// Q output is pre-scaled by 1/8*log2(e); LDS chunk-XOR swizzled (conflict fix, r17: 77->~58us).
__global__ __launch_bounds__(256) void gemm_qkv(const unsigned short* __restrict__ A,
                                                const unsigned short* __restrict__ Wc,
                                                unsigned short* __restrict__ qw,
                                                unsigned short* __restrict__ kw,
                                                unsigned short* __restrict__ vw) {
    __shared__ __align__(16) unsigned short As[2][128 * 64];
    __shared__ __align__(16) unsigned short Bs[2][128 * 64];

    const int tid  = threadIdx.x;
    const int lane = tid & 63;
    const int wid  = tid >> 6;
    const int wm = wid >> 1, wn = wid & 1;
    const int l15 = lane & 15, lg = lane >> 4;
    const int l7 = l15 & 7;

    const int tn = blockIdx.x;
    const int m0 = blockIdx.y * 128, n0 = tn * 128;

    f32x4 acc[4][4];
#pragma unroll
    for (int i = 0; i < 4; i++)
#pragma unroll
        for (int j = 0; j < 4; j++) acc[i][j] = f32x4{0.f, 0.f, 0.f, 0.f};

    const int e0 = tid * 8;
    auto STAGE = [&](int kk, int bufi) {
#pragma unroll
        for (int is = 0; is < 4; ++is) {
            int e = is * 2048 + e0;
            int row = e >> 6, c = (e >> 3) & 7;
            int col = (c ^ (row & 7)) << 3;
            gload_lds16(A  + (size_t)(m0 + row) * 1024 + kk + col, &As[bufi][e]);
            gload_lds16(Wc + (size_t)(n0 + row) * 1024 + kk + col, &Bs[bufi][e]);
        }
    };

    STAGE(0, 0);
    __syncthreads();

    for (int kk = 0; kk < 1024; kk += 64) {
        const int cur = (kk >> 6) & 1;
        if (kk + 64 < 1024) STAGE(kk + 64, cur ^ 1);
#pragma unroll
        for (int ks = 0; ks < 2; ++ks) {
            const int cso = ((ks * 4 + lg) ^ l7) << 3;   // swizzled chunk offset
            bf16x8 a[4], b[4];
#pragma unroll
            for (int f = 0; f < 4; f++) {
                a[f] = lds_frag(&As[cur][(wm * 64 + f * 16 + l15) * 64 + cso]);
                b[f] = lds_frag(&Bs[cur][(wn * 64 + f * 16 + l15) * 64 + cso]);
            }
#pragma unroll
            for (int i = 0; i < 4; i++)
#pragma unroll
                for (int j = 0; j < 4; j++)
                    acc[i][j] = __builtin_amdgcn_mfma_f32_16x16x32_bf16(a[i], b[j], acc[i][j], 0, 0, 0);
        }
        __syncthreads();
    }

    if (tn >= 16) {   // V -> (b,h,dk,s) transposed
        unsigned short* out = vw;
#pragma unroll
        for (int i = 0; i < 4; i++)
#pragma unroll
            for (int r = 0; r < 4; r++) {
                int m = m0 + wm * 64 + i * 16 + lg * 4 + r;
                int b = m >> 11, s = m & 2047;
#pragma unroll
                for (int j = 0; j < 4; j++) {
                    int n = n0 + wn * 64 + j * 16 + l15;
                    int h = (n >> 6) & 15, dk = n & 63;
                    out[((size_t)(b * NHEAD + h) * 64 + dk) * SEQ + s] = f2bf(acc[i][j][r]);
                }
            }
    } else {          // Q or K with RoPE -> (b,h,s,dk)
        unsigned short* out = (tn < 8) ? qw : kw;
        const float qscale = (tn < 8) ? 0.18033688011112042f : 1.0f;   // 1/8*log2(e) for Q
        const float L2T = 13.287712379549449f;   // log2(10000)
        float invf[4];
#pragma unroll
        for (int j = 0; j < 4; j++) {
            int idx = j * 16 + l15;          // n % 64
            int t = idx >> 1;
            invf[j] = fexp2(-((float)(2 * t) * (1.0f / 64.0f)) * L2T);
        }
        const int par = l15 & 1;
#pragma unroll
        for (int i = 0; i < 4; i++)
#pragma unroll
            for (int r = 0; r < 4; r++) {
                int m = m0 + wm * 64 + i * 16 + lg * 4 + r;
                int b = m >> 11, s = m & 2047;
                float fs = (float)s;
#pragma unroll
                for (int j = 0; j < 4; j++) {
                    float v = acc[i][j][r];
                    float other = __shfl_xor(v, 1);
                    float sn, cs;
                    __sincosf(fs * invf[j], &sn, &cs);
                    float y = par ? fmaf(v, cs, other * sn) : fmaf(v, cs, -other * sn);
                    y *= qscale;
                    int n = n0 + wn * 64 + j * 16 + l15;
                    int h = (n >> 6) & 15, dk = n & 63;
                    out[((size_t)(b * NHEAD + h) * SEQ + s) * 64 + dk] = f2bf(y);
                }
            }
    }
}

// ---------------- output GEMM: d_out = OW(8192x1024) * Wo(1024x1024)^T, fp32 out ----------------
__global__ __launch_bounds__(256) void gemm_out(const unsigned short* __restrict__ A,
                                                const unsigned short* __restrict__ W,
                                                float* __restrict__ out) {
    __shared__ __align__(16) unsigned short As[2][128 * 64];
    __shared__ __align__(16) unsigned short Bs[2][128 * 64];

    const int tid  = threadIdx.x;
    const int lane = tid & 63;
    const int wid  = tid >> 6;
    const int wm = wid >> 1, wn = wid & 1;
    const int l15 = lane & 15, lg = lane >> 4;
    const int l7 = l15 & 7;

    const int tn = blockIdx.x & 7;
    const int tm = blockIdx.x >> 3;
    const int m0 = tm * 128, n0 = tn * 128;

    f32x4 acc[4][4];
#pragma unroll
    for (int i = 0; i < 4; i++)
#pragma unroll
        for (int j = 0; j < 4; j++) acc[i][j] = f32x4{0.f, 0.f, 0.f, 0.f};

    const int e0 = tid * 8;
    auto STAGE = [&](int kk, int bufi) {
#pragma unroll
        for (int is = 0; is < 4; ++is) {
            int e = is * 2048 + e0;
            int row = e >> 6, c = (e >> 3) & 7;
            int col = (c ^ (row & 7)) << 3;
            gload_lds16(A + (size_t)(m0 + row) * 1024 + kk + col, &As[bufi][e]);
            gload_lds16(W + (size_t)(n0 + row) * 1024 + kk + col, &Bs[bufi][e]);
        }
    };

    STAGE(0, 0);
    __syncthreads();

    for (int kk = 0; kk < 1024; kk += 64) {
        const int cur = (kk >> 6) & 1;
        if (kk + 64 < 1024) STAGE(kk + 64, cur ^ 1);
#pragma unroll
        for (int ks = 0; ks < 2; ++ks) {
            const int cso = ((ks * 4 + lg) ^ l7) << 3;
            bf16x8 a[4], b[4];
#pragma unroll
            for (int f = 0; f < 4; f++) {
                a[f] = lds_frag(&As[cur][(wm * 64 + f * 16 + l15) * 64 + cso]);
                b[f] = lds_frag(&Bs[cur][(wn * 64 + f * 16 + l15) * 64 + cso]);
            }
#pragma unroll
            for (int i = 0; i < 4; i++)
#pragma unroll
                for (int j = 0; j < 4; j++)
                    acc[i][j] = __builtin_amdgcn_mfma_f32_16x16x32_bf16(a[i], b[j], acc[i][j], 0, 0, 0);
        }
        __syncthreads();
    }

#pragma unroll
    for (int i = 0; i < 4; i++)
#pragma unroll
        for (int r = 0; r < 4; r++) {
            int m = m0 + wm * 64 + i * 16 + lg * 4 + r;
            float* orow = out + (size_t)m * 1024 + n0 + wn * 64 + l15;
#pragma unroll
            for (int j = 0; j < 4; j++) orow[j * 16] = acc[i][j][r];
        }
}

// ---------------- causal flash attention: balanced pairing (tile p + tile 31-p) ----------------
// Q,K in (bh, s, dk) (Q pre-scaled by 1/8*log2e); V in (bh, dk, s). Out (b,s,dmodel) bf16.
// QK^T MFMA C-operand initialized to -mrun (scores come out max-shifted); exp2 via raw
// v_exp_f32. Row-sum l via ones-MFMA (acc5); alternating-perm p remap for iteration balance.
__global__ __launch_bounds__(256, 4) void flash_attn(const unsigned short* __restrict__ Qw,
                                                     const unsigned short* __restrict__ Kw,
                                                     const unsigned short* __restrict__ Vw,
                                                     unsigned short* __restrict__ Ow) {
    __shared__ __align__(16) unsigned short Ks[2][64 * 64];
    __shared__ __align__(16) unsigned short Vs[2][64 * 64];   // [dk][kv]
    __shared__ __align__(16) unsigned short Ps[64 * 64];      // [q][kv], swizzled, reused A/B

    const int tid  = threadIdx.x;
    const int lane = tid & 63;
    const int w    = tid >> 6;
    const int l15 = lane & 15, lg = lane >> 4;
    const int l7 = l15 & 7;

    const int logical = (blockIdx.x & 7) * 128 + (blockIdx.x >> 3);
    const int bh = logical >> 4;
    const int idx = logical & 15;
    const int g = (logical >> 5) & 15;
    const int j = (idx + g) & 15;
    const int p = (j & 1) ? (15 - (j >> 1)) : (j >> 1);   // pair: q-tiles p and 31-p
    const int qbB = 31 - p;
    const int ktmax = qbB;

    const unsigned short* Kbh = Kw + (size_t)bh * (SEQ * 64);
    const unsigned short* Vbh = Vw + (size_t)bh * (64 * SEQ);

    const int qrow0 = w * 16;
    const int prow  = qrow0 + l15;

    const unsigned short* QrowA = Qw + (size_t)bh * (SEQ * 64) + (size_t)(p * 64 + prow) * 64;
    const unsigned short* QrowB = Qw + (size_t)bh * (SEQ * 64) + (size_t)(qbB * 64 + prow) * 64;
    bf16x8 qA0 = gfrag(QrowA + lg * 8), qA1 = gfrag(QrowA + 32 + lg * 8);
    bf16x8 qB0 = gfrag(QrowB + lg * 8), qB1 = gfrag(QrowB + 32 + lg * 8);

    u16x8 onesu = {0x3F80, 0x3F80, 0x3F80, 0x3F80, 0x3F80, 0x3F80, 0x3F80, 0x3F80};
    const bf16x8 vones = __builtin_bit_cast(bf16x8, onesu);   // bf16 1.0 x8

    auto STAGE = [&](int kt2, int bufi) {
#pragma unroll
        for (int is = 0; is < 2; ++is) {
            int e = (is * 256 + tid) * 8;
            int row = e >> 6, c = (e >> 3) & 7;
            int sc = (c ^ (row & 7)) << 3;
            gload_lds16(Kbh + (size_t)kt2 * 4096 + row * 64 + sc, &Ks[bufi][e]);
            gload_lds16(Vbh + (size_t)row * SEQ + kt2 * 64 + sc, &Vs[bufi][e]);
        }
    };

    STAGE(0, 0);

    f32x4 oaccA[4], oaccB[4];
#pragma unroll
    for (int f = 0; f < 4; f++) { oaccA[f] = f32x4{0.f, 0.f, 0.f, 0.f}; oaccB[f] = f32x4{0.f, 0.f, 0.f, 0.f}; }
    f32x4 accA5 = f32x4{0.f, 0.f, 0.f, 0.f}, accB5 = f32x4{0.f, 0.f, 0.f, 0.f};   // row-sums l
    float mA = 0.f, mB = 0.f;   // running max (log2 domain), relative-shift tracked via C-init

    unsigned short* pbase = &Ps[prow * 64];
    const unsigned short* prd = &Ps[prow * 64];

    __syncthreads();

    for (int kt = 0; kt <= ktmax; ++kt) {
        const int cur = kt & 1;
        if (kt < ktmax) STAGE(kt + 1, cur ^ 1);

        auto PROC = [&](bf16x8 q0, bf16x8 q1, f32x4* oacc, f32x4& acc5, float& mrun, bool diag) {
            // S^T = K·Q with C init = -mrun: st = S - mrun directly out of the MFMA
            f32x4 st[4];
            const f32x4 cinit = {-mrun, -mrun, -mrun, -mrun};
            __builtin_amdgcn_s_setprio(1);
#pragma unroll
            for (int f = 0; f < 4; f++) {
                bf16x8 kfrag = lds_frag(&Ks[cur][(f * 16 + l15) * 64 + ((lg ^ l7) << 3)]);
                st[f] = __builtin_amdgcn_mfma_f32_16x16x32_bf16(kfrag, q0, cinit, 0, 0, 0);
            }
#pragma unroll
            for (int f = 0; f < 4; f++) {
                bf16x8 kfrag = lds_frag(&Ks[cur][(f * 16 + l15) * 64 + (((4 + lg) ^ l7) << 3)]);
                st[f] = __builtin_amdgcn_mfma_f32_16x16x32_bf16(kfrag, q1, st[f], 0, 0, 0);
            }
            __builtin_amdgcn_s_setprio(0);

            if (diag) {
#pragma unroll
                for (int f = 0; f < 4; f++)
#pragma unroll
                    for (int r = 0; r < 4; r++) {
                        int kv = f * 16 + 4 * lg + r;
                        if (kv > prow) st[f][r] = -3.0e38f;
                    }
            }

            // per-q max of (S - mrun): 7 max3 + 1 fmax in-lane, then 2 shuffles
            float m1 = max3f(st[0][0], st[0][1], st[0][2]);
            float m2 = max3f(st[0][3], st[1][0], st[1][1]);
            float m3 = max3f(st[1][2], st[1][3], st[2][0]);
            float m4 = max3f(st[2][1], st[2][2], st[2][3]);
            float m5 = max3f(st[3][0], st[3][1], st[3][2]);
            float pm = fmaxf(max3f(m1, m2, m3), max3f(m4, m5, st[3][3]));
            pm = fmaxf(pm, __shfl_xor(pm, 16));
            pm = fmaxf(pm, __shfl_xor(pm, 32));

            // defer-max (T13): rescale only when some row grew by > 8 over mrun
            if (!__all(pm <= 8.0f)) {
                float d = fmaxf(pm, 0.0f);      // per-lane shift (q = prow)
                float sc0 = fexp2(-d);
                mrun += d;
#pragma unroll
                for (int f = 0; f < 4; f++)
#pragma unroll
                    for (int r = 0; r < 4; r++) st[f][r] -= d;
#pragma unroll
                for (int r = 0; r < 4; r++) {
                    float so = __shfl(sc0, lg * 4 + r);
#pragma unroll
                    for (int f = 0; f < 4; f++) oacc[f][r] *= so;
                    acc5[r] *= so;
                }
            }

            // exp2 via single v_exp_f32 (st already max-shifted)
#pragma unroll
            for (int f = 0; f < 4; f++)
#pragma unroll
                for (int r = 0; r < 4; r++)
                    st[f][r] = fexp2(st[f][r]);

            // P -> Ps (wave-private rows; in-wave LDS ordering guards reuse)
            {
                const int halfoff = (lg & 1) << 2;
                const int cbase = lg >> 1;
#pragma unroll
                for (int f = 0; f < 4; f++) {
                    uint2 pw;
                    pw.x = cvt_pk_bf16(st[f][0], st[f][1]);
                    pw.y = cvt_pk_bf16(st[f][2], st[f][3]);
                    *(uint2*)(pbase + (((2 * f + cbase) ^ l7) << 3) + halfoff) = pw;
                }
            }

            // O += P V ; l += P * ones (acc5 in oacc register layout)
            __builtin_amdgcn_s_setprio(1);
#pragma unroll
            for (int ks = 0; ks < 2; ++ks) {
                bf16x8 pa = lds_frag(prd + (((ks * 4 + lg) ^ l7) << 3));
#pragma unroll
                for (int f = 0; f < 4; f++) {
                    bf16x8 vb = lds_frag(&Vs[cur][(f * 16 + l15) * 64 + (((ks * 4 + lg) ^ l7) << 3)]);
                    oacc[f] = __builtin_amdgcn_mfma_f32_16x16x32_bf16(pa, vb, oacc[f], 0, 0, 0);
                }
                acc5 = __builtin_amdgcn_mfma_f32_16x16x32_bf16(pa, vones, acc5, 0, 0, 0);
            }
            __builtin_amdgcn_s_setprio(0);
        };

        if (kt <= p) PROC(qA0, qA1, oaccA, accA5, mA, kt == p);
        PROC(qB0, qB1, oaccB, accB5, mB, kt == ktmax);

        __syncthreads();
    }

    const int b = bh >> 4, h = bh & 15;
#pragma unroll
    for (int r = 0; r < 4; r++) {
        float invA = 1.0f / accA5[r];
        int sgA = p * 64 + qrow0 + lg * 4 + r;
        unsigned short* orowA = Ow + ((size_t)(b * SEQ + sgA) * DMODEL) + h * 64 + l15;
#pragma unroll
        for (int f = 0; f < 4; f++) orowA[f * 16] = f2bf(oaccA[f][r] * invA);

        float invB = 1.0f / accB5[r];
        int sgB = qbB * 64 + qrow0 + lg * 4 + r;
        unsigned short* orowB = Ow + ((size_t)(b * SEQ + sgB) * DMODEL) + h * 64 + l15;
#pragma unroll
        for (int f = 0; f < 4; f++) orowB[f * 16] = f2bf(oaccB[f][r] * invB);
    }
}

extern "C" void kernel_launch(void* const* d_in, const int* in_sizes, int n_in,
                              void* d_out, int out_size, void* d_ws, size_t ws_size,
                              hipStream_t stream) {
    const float* x  = (const float*)d_in[0];
    const float* wq = (const float*)d_in[1];
    const float* wk = (const float*)d_in[2];
    const float* wv = (const float*)d_in[3];
    const float* wo = (const float*)d_in[4];

    unsigned short* ws = (unsigned short*)d_ws;
    const size_t MEL = (size_t)8192 * 1024;   // 8M elements
    const size_t WEL = (size_t)1024 * 1024;   // 1M elements
    unsigned short* xb  = ws;
    unsigned short* wqb = xb + MEL;           // 4 weights contiguous: wq|wk|wv|wo
    unsigned short* wob = wqb + 3 * WEL;
    unsigned short* qw  = wob + WEL;
    unsigned short* kw  = qw + MEL;
    unsigned short* vw  = kw + MEL;
    unsigned short* ow  = vw + MEL;

    cvt_all<<<12288, 256, 0, stream>>>(x, wq, wk, wv, wo, xb, wqb);

    gemm_qkv<<<dim3(24, 64), 256, 0, stream>>>(xb, wqb, qw, kw, vw);

    flash_attn<<<1024, 256, 0, stream>>>(qw, kw, vw, ow);

    gemm_out<<<512, 256, 0, stream>>>(ow, wob, (float*)d_out);
}